// Round 1
// baseline (550.414 us; speedup 1.0000x reference)
//
#include <hip/hip_runtime.h>

#define N_NODES   50000
#define N_EDGES   800000
#define F_INF     128
#define HF        128      // HEADS * F_HEAD
#define N_CLASSES 32
#define NEG_SLOPE 0.2f

__device__ __forceinline__ float leaky(float x) {
    return x > 0.f ? x : x * NEG_SLOPE;
}

// ---------------- CSR build ----------------
__global__ void k_deg(const int* __restrict__ dst, int* __restrict__ deg) {
    int i = blockIdx.x * blockDim.x + threadIdx.x;
    if (i < N_EDGES) atomicAdd(&deg[dst[i]], 1);
}

// single-block exclusive scan over N_NODES degrees -> row_ptr (+ cursor copy)
__global__ __launch_bounds__(1024) void k_scan(const int* __restrict__ deg,
                                               int* __restrict__ row_ptr,
                                               int* __restrict__ cursor) {
    __shared__ int part[1024];
    const int tid = threadIdx.x;
    const int CH = (N_NODES + 1023) / 1024;   // 49
    const int b = tid * CH;
    int s = 0;
    for (int i = 0; i < CH; ++i) {
        int idx = b + i;
        if (idx < N_NODES) s += deg[idx];
    }
    part[tid] = s;
    __syncthreads();
    // Hillis-Steele inclusive scan over 1024 partials
    for (int off = 1; off < 1024; off <<= 1) {
        int v = part[tid];
        int add = (tid >= off) ? part[tid - off] : 0;
        __syncthreads();
        part[tid] = v + add;
        __syncthreads();
    }
    int prefix = (tid == 0) ? 0 : part[tid - 1];
    for (int i = 0; i < CH; ++i) {
        int idx = b + i;
        if (idx < N_NODES) {
            row_ptr[idx] = prefix;
            cursor[idx]  = prefix;
            prefix += deg[idx];
        }
    }
    if (tid == 1023) row_ptr[N_NODES] = part[1023];
}

__global__ void k_scatter(const int* __restrict__ src, const int* __restrict__ dst,
                          int* __restrict__ cursor, int* __restrict__ csr_src) {
    int i = blockIdx.x * blockDim.x + threadIdx.x;
    if (i < N_EDGES) {
        int d = dst[i];
        int pos = atomicAdd(&cursor[d], 1);
        csr_src[pos] = src[i];
    }
}

// ---------------- GEMM1: h1 = x @ W1 (+ fused al_src/al_dst) ----------------
// blockIdx&1 selects which 64 output cols; grid-stride over 8-row tiles.
__global__ __launch_bounds__(256) void k_gemm1(
    const float* __restrict__ x, const float* __restrict__ W1,
    const float* __restrict__ a_src, const float* __restrict__ a_dst,
    float* __restrict__ h1, float* __restrict__ al_src, float* __restrict__ al_dst)
{
    __shared__ float Ws[128 * 64];   // 32 KB: W1[k][half*64 + c]
    __shared__ float xs[8 * 128];    // 4 KB: 8 rows of x
    const int tid  = threadIdx.x;
    const int half = blockIdx.x & 1;
    const int c    = tid & 63;
    const int r0   = tid >> 6;       // 0..3
    for (int k0 = 0; k0 < 128; k0 += 4) {
        int k = k0 + r0;
        Ws[k * 64 + c] = W1[k * 128 + half * 64 + c];
    }
    const int   gc = half * 64 + c;
    const float as = a_src[gc], ad = a_dst[gc];
    const int   h  = gc >> 4;        // head index
    const int ntiles = N_NODES / 8;  // 6250 exactly
    for (int t = (int)(blockIdx.x >> 1); t < ntiles; t += (int)(gridDim.x >> 1)) {
        __syncthreads();
        for (int i = tid; i < 1024; i += 256) xs[i] = x[t * 1024 + i];
        __syncthreads();
        float acc0 = 0.f, acc1 = 0.f;
        const float* xr0 = &xs[r0 * 128];
        const float* xr1 = &xs[(r0 + 4) * 128];
        #pragma unroll 8
        for (int k = 0; k < 128; ++k) {
            float w = Ws[k * 64 + c];
            acc0 = fmaf(xr0[k], w, acc0);
            acc1 = fmaf(xr1[k], w, acc1);
        }
        #pragma unroll
        for (int which = 0; which < 2; ++which) {
            float v  = which ? acc1 : acc0;
            int  row = t * 8 + r0 + which * 4;
            h1[row * 128 + gc] = v;
            float s = v * as, d = v * ad;
            for (int off = 8; off; off >>= 1) {   // reduce within 16-lane head group
                s += __shfl_xor(s, off);
                d += __shfl_xor(d, off);
            }
            if ((c & 15) == 0) {
                al_src[row * 8 + h] = s;
                al_dst[row * 8 + h] = d;
            }
        }
    }
}

// ---------------- agg1: softmax-weighted gather + bias + ELU ----------------
// one block (128 threads) per node; thread = (head h = c>>4, feat f = c&15)
__global__ __launch_bounds__(128) void k_agg1(
    const float* __restrict__ h1, const float* __restrict__ al_src,
    const float* __restrict__ al_dst, const int* __restrict__ row_ptr,
    const int* __restrict__ csr_src, const float* __restrict__ b1,
    float* __restrict__ h2)
{
    const int n = blockIdx.x;
    const int c = threadIdx.x;
    const int h = c >> 4;
    const float alD = al_dst[n * 8 + h];
    // self loop
    float e = leaky(al_src[n * 8 + h] + alD);
    float w = __expf(e);
    float denom = w;
    float acc = w * h1[n * 128 + c];
    const int beg = row_ptr[n], end = row_ptr[n + 1];
    for (int j = beg; j < end; ++j) {
        int s = csr_src[j];
        float e2 = leaky(al_src[s * 8 + h] + alD);
        float w2 = __expf(e2);
        denom += w2;
        acc = fmaf(w2, h1[s * 128 + c], acc);
    }
    float o = acc / denom + b1[c];
    o = o > 0.f ? o : expm1f(o);     // ELU
    h2[n * 128 + c] = o;
}

// ---------------- GEMM2: t2 = h2 @ W2 (+ fused al2) ----------------
__global__ __launch_bounds__(256) void k_gemm2(
    const float* __restrict__ h2, const float* __restrict__ W2,
    const float* __restrict__ a_src, const float* __restrict__ a_dst,
    float* __restrict__ t2, float* __restrict__ al_src, float* __restrict__ al_dst)
{
    __shared__ float Ws[128 * 32];   // 16 KB
    __shared__ float xs[8 * 128];    // 4 KB
    const int tid = threadIdx.x;
    const int c  = tid & 31;
    const int r0 = tid >> 5;         // 0..7
    for (int i = tid; i < 128 * 32; i += 256) Ws[i] = W2[i];
    const float as = a_src[c], ad = a_dst[c];
    const int ntiles = N_NODES / 8;
    for (int t = (int)blockIdx.x; t < ntiles; t += (int)gridDim.x) {
        __syncthreads();
        for (int i = tid; i < 1024; i += 256) xs[i] = h2[t * 1024 + i];
        __syncthreads();
        float acc = 0.f;
        const float* xr = &xs[r0 * 128];
        #pragma unroll 8
        for (int k = 0; k < 128; ++k)
            acc = fmaf(xr[k], Ws[k * 32 + c], acc);
        int row = t * 8 + r0;
        t2[row * 32 + c] = acc;
        float s = acc * as, d = acc * ad;
        for (int off = 16; off; off >>= 1) {  // reduce within 32-lane row group
            s += __shfl_xor(s, off);
            d += __shfl_xor(d, off);
        }
        if (c == 0) {
            al_src[row] = s;
            al_dst[row] = d;
        }
    }
}

// ---------------- agg2: layer-2 gather + bias + log_softmax -> out ----------------
// one block (64 threads) per node; two 32-lane halves split the edge list.
__global__ __launch_bounds__(64) void k_agg2(
    const float* __restrict__ t2, const float* __restrict__ al_src,
    const float* __restrict__ al_dst, const int* __restrict__ row_ptr,
    const int* __restrict__ csr_src, const float* __restrict__ b2,
    float* __restrict__ out)
{
    const int n = blockIdx.x;
    const int t = threadIdx.x;
    const int f = t & 31;
    const int half = t >> 5;
    const float alD = al_dst[n];
    float denom = 0.f, acc = 0.f;
    if (half == 0) {   // self loop counted once
        float e = leaky(al_src[n] + alD);
        float w = __expf(e);
        denom = w;
        acc = w * t2[n * 32 + f];
    }
    const int beg = row_ptr[n], end = row_ptr[n + 1];
    for (int j = beg + half; j < end; j += 2) {
        int s = csr_src[j];
        float e = leaky(al_src[s] + alD);
        float w = __expf(e);
        denom += w;
        acc = fmaf(w, t2[s * 32 + f], acc);
    }
    acc   += __shfl_xor(acc, 32);
    denom += __shfl_xor(denom, 32);
    float o = acc / denom + b2[f];
    // log_softmax over the 32 classes (both halves hold identical o)
    float m = o;
    for (int off = 16; off; off >>= 1) m = fmaxf(m, __shfl_xor(m, off));
    float ex = __expf(o - m);
    float ssum = ex;
    for (int off = 16; off; off >>= 1) ssum += __shfl_xor(ssum, off);
    float res = (o - m) - __logf(ssum);
    if (half == 0) out[n * 32 + f] = res;
}

extern "C" void kernel_launch(void* const* d_in, const int* in_sizes, int n_in,
                              void* d_out, int out_size, void* d_ws, size_t ws_size,
                              hipStream_t stream) {
    const float* x      = (const float*)d_in[0];
    const int*   src    = (const int*)d_in[1];
    const int*   dst    = (const int*)d_in[2];
    const float* W1     = (const float*)d_in[3];
    const float* a_src1 = (const float*)d_in[4];
    const float* a_dst1 = (const float*)d_in[5];
    const float* b1     = (const float*)d_in[6];
    const float* W2     = (const float*)d_in[7];
    const float* a_src2 = (const float*)d_in[8];
    const float* a_dst2 = (const float*)d_in[9];
    const float* b2     = (const float*)d_in[10];
    float* out = (float*)d_out;

    char* ws = (char*)d_ws;
    size_t off = 0;
    auto alloc = [&](size_t bytes) {
        void* p = ws + off;
        off += (bytes + 255) & ~(size_t)255;
        return p;
    };
    float* h1     = (float*)alloc((size_t)N_NODES * 128 * 4);
    float* h2     = (float*)alloc((size_t)N_NODES * 128 * 4);
    float* t2     = (float*)alloc((size_t)N_NODES * 32 * 4);
    float* alS1   = (float*)alloc((size_t)N_NODES * 8 * 4);
    float* alD1   = (float*)alloc((size_t)N_NODES * 8 * 4);
    float* alS2   = (float*)alloc((size_t)N_NODES * 4);
    float* alD2   = (float*)alloc((size_t)N_NODES * 4);
    int*   deg    = (int*)alloc((size_t)N_NODES * 4);
    int*   rowp   = (int*)alloc((size_t)(N_NODES + 1) * 4);
    int*   cursor = (int*)alloc((size_t)N_NODES * 4);
    int*   csr    = (int*)alloc((size_t)N_EDGES * 4);
    (void)ws_size; (void)in_sizes; (void)n_in; (void)out_size;

    hipMemsetAsync(deg, 0, (size_t)N_NODES * 4, stream);
    k_deg<<<(N_EDGES + 255) / 256, 256, 0, stream>>>(dst, deg);
    k_scan<<<1, 1024, 0, stream>>>(deg, rowp, cursor);
    k_scatter<<<(N_EDGES + 255) / 256, 256, 0, stream>>>(src, dst, cursor, csr);
    k_gemm1<<<1024, 256, 0, stream>>>(x, W1, a_src1, a_dst1, h1, alS1, alD1);
    k_agg1<<<N_NODES, 128, 0, stream>>>(h1, alS1, alD1, rowp, csr, b1, h2);
    k_gemm2<<<512, 256, 0, stream>>>(h2, W2, a_src2, a_dst2, t2, alS2, alD2);
    k_agg2<<<N_NODES, 64, 0, stream>>>(t2, alS2, alD2, rowp, csr, b2, out);
}

// Round 2
// 405.449 us; speedup vs baseline: 1.3575x; 1.3575x over previous
//
#include <hip/hip_runtime.h>

#define N_NODES   50000
#define N_EDGES   800000
#define NEG_SLOPE 0.2f
#define SCAN_NBLK 49          // ceil(50000/1024)

__device__ __forceinline__ float leaky(float x) {
    return x > 0.f ? x : x * NEG_SLOPE;
}

// ---------------- CSR build ----------------
__global__ void k_deg(const int* __restrict__ dst, int* __restrict__ deg) {
    int i = blockIdx.x * blockDim.x + threadIdx.x;
    if (i < N_EDGES) atomicAdd(&deg[dst[i]], 1);
}

// pass 1: per-block (1024-chunk) sums of deg
__global__ __launch_bounds__(1024) void k_scan_part(const int* __restrict__ deg,
                                                    int* __restrict__ partial) {
    __shared__ int red[1024];
    const int b = blockIdx.x, tid = threadIdx.x;
    const int idx = b * 1024 + tid;
    red[tid] = (idx < N_NODES) ? deg[idx] : 0;
    __syncthreads();
    for (int off = 512; off; off >>= 1) {
        if (tid < off) red[tid] += red[tid + off];
        __syncthreads();
    }
    if (tid == 0) partial[b] = red[0];
}

// pass 2: block-local scan + offset from partials -> row_ptr, cursor
__global__ __launch_bounds__(1024) void k_scan_apply(const int* __restrict__ deg,
                                                     const int* __restrict__ partial,
                                                     int* __restrict__ row_ptr,
                                                     int* __restrict__ cursor) {
    __shared__ int sh[1024];
    __shared__ int psh[64];
    __shared__ int blockoff_sh;
    const int b = blockIdx.x, tid = threadIdx.x;
    if (tid < 64) psh[tid] = (tid < SCAN_NBLK) ? partial[tid] : 0;
    const int idx = b * 1024 + tid;
    const int v = (idx < N_NODES) ? deg[idx] : 0;
    sh[tid] = v;
    __syncthreads();
    if (tid == 0) {
        int s = 0;
        for (int i = 0; i < b; ++i) s += psh[i];
        blockoff_sh = s;
    }
    // Hillis-Steele inclusive scan over 1024 elements
    for (int off = 1; off < 1024; off <<= 1) {
        int add = (tid >= off) ? sh[tid - off] : 0;
        __syncthreads();
        sh[tid] += add;
        __syncthreads();
    }
    const int incl = sh[tid];
    const int base = blockoff_sh;   // valid: written before first scan sync round
    if (idx < N_NODES) {
        int excl = base + incl - v;
        row_ptr[idx] = excl;
        cursor[idx]  = excl;
    }
    if (b == SCAN_NBLK - 1 && tid == 1023) row_ptr[N_NODES] = base + incl;
}

__global__ void k_scatter(const int* __restrict__ src, const int* __restrict__ dst,
                          int* __restrict__ cursor, int* __restrict__ csr_src) {
    int i = blockIdx.x * blockDim.x + threadIdx.x;
    if (i < N_EDGES) {
        int d = dst[i];
        int pos = atomicAdd(&cursor[d], 1);
        csr_src[pos] = src[i];
    }
}

// ---------------- GEMM1: h1 = x @ W1 (+ fused al_src/al_dst) ----------------
__global__ __launch_bounds__(256) void k_gemm1(
    const float* __restrict__ x, const float* __restrict__ W1,
    const float* __restrict__ a_src, const float* __restrict__ a_dst,
    float* __restrict__ h1, float* __restrict__ al_src, float* __restrict__ al_dst)
{
    __shared__ float Ws[128 * 64];   // 32 KB
    __shared__ float xs[8 * 128];    // 4 KB
    const int tid  = threadIdx.x;
    const int half = blockIdx.x & 1;
    const int c    = tid & 63;
    const int r0   = tid >> 6;       // 0..3
    for (int k0 = 0; k0 < 128; k0 += 4) {
        int k = k0 + r0;
        Ws[k * 64 + c] = W1[k * 128 + half * 64 + c];
    }
    const int   gc = half * 64 + c;
    const float as = a_src[gc], ad = a_dst[gc];
    const int   h  = gc >> 4;        // head index
    const int ntiles = N_NODES / 8;  // 6250 exactly
    for (int t = (int)(blockIdx.x >> 1); t < ntiles; t += (int)(gridDim.x >> 1)) {
        __syncthreads();
        for (int i = tid; i < 1024; i += 256) xs[i] = x[t * 1024 + i];
        __syncthreads();
        float acc0 = 0.f, acc1 = 0.f;
        const float* xr0 = &xs[r0 * 128];
        const float* xr1 = &xs[(r0 + 4) * 128];
        #pragma unroll 8
        for (int k = 0; k < 128; ++k) {
            float w = Ws[k * 64 + c];
            acc0 = fmaf(xr0[k], w, acc0);
            acc1 = fmaf(xr1[k], w, acc1);
        }
        #pragma unroll
        for (int which = 0; which < 2; ++which) {
            float v  = which ? acc1 : acc0;
            int  row = t * 8 + r0 + which * 4;
            h1[row * 128 + gc] = v;
            float s = v * as, d = v * ad;
            for (int off = 8; off; off >>= 1) {
                s += __shfl_xor(s, off);
                d += __shfl_xor(d, off);
            }
            if ((c & 15) == 0) {
                al_src[row * 8 + h] = s;
                al_dst[row * 8 + h] = d;
            }
        }
    }
}

// ---------------- agg1: softmax-weighted gather + bias + ELU ----------------
// one block (128 threads) per node; thread = (head h = c>>4, feat f = c&15)
// exp deduped: per chunk of 16 edges, 128 threads compute the 16x8 weights once.
__global__ __launch_bounds__(128) void k_agg1(
    const float* __restrict__ h1, const float* __restrict__ al_src,
    const float* __restrict__ al_dst, const int* __restrict__ row_ptr,
    const int* __restrict__ csr_src, const float* __restrict__ b1,
    float* __restrict__ h2)
{
    const int n = blockIdx.x;
    const int c = threadIdx.x;
    const int h = c >> 4;
    __shared__ float alD_sh[8];
    __shared__ float w_sh[16 * 8];
    __shared__ int   s_sh[16];
    if (c < 8) alD_sh[c] = al_dst[n * 8 + c];
    __syncthreads();
    const float alD = alD_sh[h];
    // self loop
    float w = __expf(leaky(al_src[n * 8 + h] + alD));
    float denom = w;
    float acc = w * h1[n * 128 + c];
    const int beg = row_ptr[n], end = row_ptr[n + 1];
    const int e_local = c >> 3, h_w = c & 7;
    for (int j0 = beg; j0 < end; j0 += 16) {
        const int nE = min(16, end - j0);
        if (e_local < nE) {
            int s = csr_src[j0 + e_local];
            if (h_w == 0) s_sh[e_local] = s;
            w_sh[e_local * 8 + h_w] =
                __expf(leaky(al_src[s * 8 + h_w] + alD_sh[h_w]));
        }
        __syncthreads();
        for (int e = 0; e < nE; ++e) {
            float we = w_sh[e * 8 + h];     // broadcast within head group
            int   s  = s_sh[e];             // broadcast
            denom += we;
            acc = fmaf(we, h1[s * 128 + c], acc);
        }
        __syncthreads();
    }
    float o = acc / denom + b1[c];
    o = o > 0.f ? o : expm1f(o);     // ELU
    h2[n * 128 + c] = o;
}

// ---------------- GEMM2: t2 = h2 @ W2 (+ fused al2) ----------------
__global__ __launch_bounds__(256) void k_gemm2(
    const float* __restrict__ h2, const float* __restrict__ W2,
    const float* __restrict__ a_src, const float* __restrict__ a_dst,
    float* __restrict__ t2, float* __restrict__ al_src, float* __restrict__ al_dst)
{
    __shared__ float Ws[128 * 32];   // 16 KB
    __shared__ float xs[8 * 128];    // 4 KB
    const int tid = threadIdx.x;
    const int c  = tid & 31;
    const int r0 = tid >> 5;         // 0..7
    for (int i = tid; i < 128 * 32; i += 256) Ws[i] = W2[i];
    const float as = a_src[c], ad = a_dst[c];
    const int ntiles = N_NODES / 8;
    for (int t = (int)blockIdx.x; t < ntiles; t += (int)gridDim.x) {
        __syncthreads();
        for (int i = tid; i < 1024; i += 256) xs[i] = h2[t * 1024 + i];
        __syncthreads();
        float acc = 0.f;
        const float* xr = &xs[r0 * 128];
        #pragma unroll 8
        for (int k = 0; k < 128; ++k)
            acc = fmaf(xr[k], Ws[k * 32 + c], acc);
        int row = t * 8 + r0;
        t2[row * 32 + c] = acc;
        float s = acc * as, d = acc * ad;
        for (int off = 16; off; off >>= 1) {
            s += __shfl_xor(s, off);
            d += __shfl_xor(d, off);
        }
        if (c == 0) {
            al_src[row] = s;
            al_dst[row] = d;
        }
    }
}

// ---------------- agg2: layer-2 gather + bias + log_softmax -> out ----------------
__global__ __launch_bounds__(64) void k_agg2(
    const float* __restrict__ t2, const float* __restrict__ al_src,
    const float* __restrict__ al_dst, const int* __restrict__ row_ptr,
    const int* __restrict__ csr_src, const float* __restrict__ b2,
    float* __restrict__ out)
{
    const int n = blockIdx.x;
    const int t = threadIdx.x;
    const int f = t & 31;
    const int half = t >> 5;
    const float alD = al_dst[n];
    float denom = 0.f, acc = 0.f;
    if (half == 0) {   // self loop counted once
        float e = leaky(al_src[n] + alD);
        float w = __expf(e);
        denom = w;
        acc = w * t2[n * 32 + f];
    }
    const int beg = row_ptr[n], end = row_ptr[n + 1];
    for (int j = beg + half; j < end; j += 2) {
        int s = csr_src[j];
        float e = leaky(al_src[s] + alD);
        float w = __expf(e);
        denom += w;
        acc = fmaf(w, t2[s * 32 + f], acc);
    }
    acc   += __shfl_xor(acc, 32);
    denom += __shfl_xor(denom, 32);
    float o = acc / denom + b2[f];
    float m = o;
    for (int off = 16; off; off >>= 1) m = fmaxf(m, __shfl_xor(m, off));
    float ex = __expf(o - m);
    float ssum = ex;
    for (int off = 16; off; off >>= 1) ssum += __shfl_xor(ssum, off);
    float res = (o - m) - __logf(ssum);
    if (half == 0) out[n * 32 + f] = res;
}

extern "C" void kernel_launch(void* const* d_in, const int* in_sizes, int n_in,
                              void* d_out, int out_size, void* d_ws, size_t ws_size,
                              hipStream_t stream) {
    const float* x      = (const float*)d_in[0];
    const int*   src    = (const int*)d_in[1];
    const int*   dst    = (const int*)d_in[2];
    const float* W1     = (const float*)d_in[3];
    const float* a_src1 = (const float*)d_in[4];
    const float* a_dst1 = (const float*)d_in[5];
    const float* b1     = (const float*)d_in[6];
    const float* W2     = (const float*)d_in[7];
    const float* a_src2 = (const float*)d_in[8];
    const float* a_dst2 = (const float*)d_in[9];
    const float* b2     = (const float*)d_in[10];
    float* out = (float*)d_out;

    char* ws = (char*)d_ws;
    size_t off = 0;
    auto alloc = [&](size_t bytes) {
        void* p = ws + off;
        off += (bytes + 255) & ~(size_t)255;
        return p;
    };
    float* h1      = (float*)alloc((size_t)N_NODES * 128 * 4);
    float* h2      = (float*)alloc((size_t)N_NODES * 128 * 4);
    float* t2      = (float*)alloc((size_t)N_NODES * 32 * 4);
    float* alS1    = (float*)alloc((size_t)N_NODES * 8 * 4);
    float* alD1    = (float*)alloc((size_t)N_NODES * 8 * 4);
    float* alS2    = (float*)alloc((size_t)N_NODES * 4);
    float* alD2    = (float*)alloc((size_t)N_NODES * 4);
    int*   deg     = (int*)alloc((size_t)N_NODES * 4);
    int*   rowp    = (int*)alloc((size_t)(N_NODES + 1) * 4);
    int*   cursor  = (int*)alloc((size_t)N_NODES * 4);
    int*   csr     = (int*)alloc((size_t)N_EDGES * 4);
    int*   partial = (int*)alloc((size_t)SCAN_NBLK * 4);
    (void)ws_size; (void)in_sizes; (void)n_in; (void)out_size;

    hipMemsetAsync(deg, 0, (size_t)N_NODES * 4, stream);
    k_deg<<<(N_EDGES + 255) / 256, 256, 0, stream>>>(dst, deg);
    k_scan_part<<<SCAN_NBLK, 1024, 0, stream>>>(deg, partial);
    k_scan_apply<<<SCAN_NBLK, 1024, 0, stream>>>(deg, partial, rowp, cursor);
    k_scatter<<<(N_EDGES + 255) / 256, 256, 0, stream>>>(src, dst, cursor, csr);
    k_gemm1<<<1024, 256, 0, stream>>>(x, W1, a_src1, a_dst1, h1, alS1, alD1);
    k_agg1<<<N_NODES, 128, 0, stream>>>(h1, alS1, alD1, rowp, csr, b1, h2);
    k_gemm2<<<512, 256, 0, stream>>>(h2, W2, a_src2, a_dst2, t2, alS2, alD2);
    k_agg2<<<N_NODES, 64, 0, stream>>>(t2, alS2, alD2, rowp, csr, b2, out);
}

// Round 3
// 341.743 us; speedup vs baseline: 1.6106x; 1.1864x over previous
//
#include <hip/hip_runtime.h>

#define N_NODES   50000
#define N_EDGES   800000
#define NEG_SLOPE 0.2f
#define SCAN_NBLK 49          // ceil(50000/1024)

__device__ __forceinline__ float leaky(float x) {
    return x > 0.f ? x : x * NEG_SLOPE;
}

__device__ __forceinline__ void fma4(float4& acc, const float4 a,
                                     const float4 w0, const float4 w1,
                                     const float4 w2, const float4 w3) {
    acc.x = fmaf(a.x, w0.x, fmaf(a.y, w1.x, fmaf(a.z, w2.x, fmaf(a.w, w3.x, acc.x))));
    acc.y = fmaf(a.x, w0.y, fmaf(a.y, w1.y, fmaf(a.z, w2.y, fmaf(a.w, w3.y, acc.y))));
    acc.z = fmaf(a.x, w0.z, fmaf(a.y, w1.z, fmaf(a.z, w2.z, fmaf(a.w, w3.z, acc.z))));
    acc.w = fmaf(a.x, w0.w, fmaf(a.y, w1.w, fmaf(a.z, w2.w, fmaf(a.w, w3.w, acc.w))));
}

__device__ __forceinline__ float dot4(const float4 a, const float4 b) {
    return a.x * b.x + a.y * b.y + a.z * b.z + a.w * b.w;
}

// ---------------- CSR build ----------------
__global__ void k_deg(const int* __restrict__ dst, int* __restrict__ deg) {
    int i = blockIdx.x * blockDim.x + threadIdx.x;
    if (i < N_EDGES) atomicAdd(&deg[dst[i]], 1);
}

__global__ __launch_bounds__(1024) void k_scan_part(const int* __restrict__ deg,
                                                    int* __restrict__ partial) {
    __shared__ int red[1024];
    const int b = blockIdx.x, tid = threadIdx.x;
    const int idx = b * 1024 + tid;
    red[tid] = (idx < N_NODES) ? deg[idx] : 0;
    __syncthreads();
    for (int off = 512; off; off >>= 1) {
        if (tid < off) red[tid] += red[tid + off];
        __syncthreads();
    }
    if (tid == 0) partial[b] = red[0];
}

__global__ __launch_bounds__(1024) void k_scan_apply(const int* __restrict__ deg,
                                                     const int* __restrict__ partial,
                                                     int* __restrict__ row_ptr,
                                                     int* __restrict__ cursor) {
    __shared__ int sh[1024];
    __shared__ int psh[64];
    __shared__ int blockoff_sh;
    const int b = blockIdx.x, tid = threadIdx.x;
    if (tid < 64) psh[tid] = (tid < SCAN_NBLK) ? partial[tid] : 0;
    const int idx = b * 1024 + tid;
    const int v = (idx < N_NODES) ? deg[idx] : 0;
    sh[tid] = v;
    __syncthreads();
    if (tid == 0) {
        int s = 0;
        for (int i = 0; i < b; ++i) s += psh[i];
        blockoff_sh = s;
    }
    for (int off = 1; off < 1024; off <<= 1) {
        int add = (tid >= off) ? sh[tid - off] : 0;
        __syncthreads();
        sh[tid] += add;
        __syncthreads();
    }
    const int incl = sh[tid];
    const int base = blockoff_sh;
    if (idx < N_NODES) {
        int excl = base + incl - v;
        row_ptr[idx] = excl;
        cursor[idx]  = excl;
    }
    if (b == SCAN_NBLK - 1 && tid == 1023) row_ptr[N_NODES] = base + incl;
}

__global__ void k_scatter(const int* __restrict__ src, const int* __restrict__ dst,
                          int* __restrict__ cursor, int* __restrict__ csr_src) {
    int i = blockIdx.x * blockDim.x + threadIdx.x;
    if (i < N_EDGES) {
        int d = dst[i];
        int pos = atomicAdd(&cursor[d], 1);
        csr_src[pos] = src[i];
    }
}

// ---------------- GEMM1: h1 = x @ W1 (+ fused al_src/al_dst) ----------------
// Block: 64-row x 64-col tile (col half selected by blockIdx&1).
// Thread: 4x4 outputs; both operands via ds_read_b128; xs XOR-swizzled.
__global__ __launch_bounds__(256) void k_gemm1(
    const float* __restrict__ x, const float* __restrict__ W1,
    const float* __restrict__ a_src, const float* __restrict__ a_dst,
    float* __restrict__ h1, float* __restrict__ al_src, float* __restrict__ al_dst)
{
    __shared__ float4 xs4[64 * 32];   // 32 KB, [r][k4 ^ ((r>>2)&7)]
    __shared__ float4 ws4[128 * 16];  // 32 KB, [k][c4]
    const int tid  = threadIdx.x;
    const int half = blockIdx.x & 1;
    const int row0 = (int)(blockIdx.x >> 1) * 64;
    const int tc   = tid & 15;        // col group: cols half*64 + 4*tc .. +3
    const int tr   = tid >> 4;        // row group: rows row0 + 4*tr .. +3
    const float4* x4  = (const float4*)x;
    const float4* W14 = (const float4*)W1;

    #pragma unroll
    for (int p = 0; p < 8; ++p) {     // stage W half: 128k x 16 f4
        int i = tid + p * 256;
        int k = i >> 4, c4 = i & 15;
        ws4[k * 16 + c4] = W14[k * 32 + half * 16 + c4];
    }
    #pragma unroll
    for (int p = 0; p < 8; ++p) {     // stage x tile: 64r x 32 f4 (swizzled)
        int i = tid + p * 256;
        int r = i >> 5, k4 = i & 31;
        int gr = row0 + r; if (gr > N_NODES - 1) gr = N_NODES - 1;
        xs4[r * 32 + (k4 ^ ((r >> 2) & 7))] = x4[gr * 32 + k4];
    }
    __syncthreads();

    float4 acc[4];
    #pragma unroll
    for (int i = 0; i < 4; ++i) acc[i] = make_float4(0.f, 0.f, 0.f, 0.f);
    const int sw = tr & 7;
    #pragma unroll 2
    for (int k4 = 0; k4 < 32; ++k4) {
        float4 w0 = ws4[(4 * k4 + 0) * 16 + tc];
        float4 w1 = ws4[(4 * k4 + 1) * 16 + tc];
        float4 w2 = ws4[(4 * k4 + 2) * 16 + tc];
        float4 w3 = ws4[(4 * k4 + 3) * 16 + tc];
        const int kk = k4 ^ sw;
        #pragma unroll
        for (int i = 0; i < 4; ++i) {
            float4 a = xs4[(4 * tr + i) * 32 + kk];
            fma4(acc[i], a, w0, w1, w2, w3);
        }
    }

    const int c0   = half * 64 + 4 * tc;
    const int head = c0 >> 4;
    const float4 as4 = ((const float4*)a_src)[half * 16 + tc];
    const float4 ad4 = ((const float4*)a_dst)[half * 16 + tc];
    #pragma unroll
    for (int i = 0; i < 4; ++i) {
        int r = row0 + 4 * tr + i;
        if (r < N_NODES) {
            ((float4*)h1)[r * 32 + (c0 >> 2)] = acc[i];
            float s = dot4(acc[i], as4);
            float d = dot4(acc[i], ad4);
            s += __shfl_xor(s, 1); s += __shfl_xor(s, 2);
            d += __shfl_xor(d, 1); d += __shfl_xor(d, 2);
            if ((tc & 3) == 0) {
                al_src[r * 8 + head] = s;
                al_dst[r * 8 + head] = d;
            }
        }
    }
}

// ---------------- agg1: softmax-weighted gather + bias + ELU ----------------
__global__ __launch_bounds__(128) void k_agg1(
    const float* __restrict__ h1, const float* __restrict__ al_src,
    const float* __restrict__ al_dst, const int* __restrict__ row_ptr,
    const int* __restrict__ csr_src, const float* __restrict__ b1,
    float* __restrict__ h2)
{
    const int n = blockIdx.x;
    const int c = threadIdx.x;
    const int h = c >> 4;
    __shared__ float alD_sh[8];
    __shared__ float w_sh[16 * 8];
    __shared__ int   s_sh[16];
    if (c < 8) alD_sh[c] = al_dst[n * 8 + c];
    __syncthreads();
    const float alD = alD_sh[h];
    float w = __expf(leaky(al_src[n * 8 + h] + alD));
    float denom = w;
    float acc = w * h1[n * 128 + c];
    const int beg = row_ptr[n], end = row_ptr[n + 1];
    const int e_local = c >> 3, h_w = c & 7;
    for (int j0 = beg; j0 < end; j0 += 16) {
        const int nE = min(16, end - j0);
        if (e_local < nE) {
            int s = csr_src[j0 + e_local];
            if (h_w == 0) s_sh[e_local] = s;
            w_sh[e_local * 8 + h_w] =
                __expf(leaky(al_src[s * 8 + h_w] + alD_sh[h_w]));
        }
        __syncthreads();
        for (int e = 0; e < nE; ++e) {
            float we = w_sh[e * 8 + h];
            int   s  = s_sh[e];
            denom += we;
            acc = fmaf(we, h1[s * 128 + c], acc);
        }
        __syncthreads();
    }
    float o = acc / denom + b1[c];
    o = o > 0.f ? o : expm1f(o);
    h2[n * 128 + c] = o;
}

// ---------------- GEMM2: t2 = h2 @ W2 (+ fused al2) ----------------
// Block: 64-row x 32-col tile, 128 threads, 4x4 per thread.
__global__ __launch_bounds__(128) void k_gemm2(
    const float* __restrict__ h2, const float* __restrict__ W2,
    const float* __restrict__ a_src, const float* __restrict__ a_dst,
    float* __restrict__ t2, float* __restrict__ al_src, float* __restrict__ al_dst)
{
    __shared__ float4 xs4[64 * 32];  // 32 KB (swizzled)
    __shared__ float4 ws4[128 * 8];  // 16 KB
    const int tid  = threadIdx.x;
    const int row0 = (int)blockIdx.x * 64;
    const int tc   = tid & 7;        // cols 4*tc .. +3
    const int tr   = tid >> 3;       // rows row0 + 4*tr .. +3
    const float4* h24 = (const float4*)h2;
    const float4* W24 = (const float4*)W2;

    #pragma unroll
    for (int p = 0; p < 8; ++p) {    // W2: 128x32 = 1024 f4
        int i = tid + p * 128;
        ws4[i] = W24[i];
    }
    #pragma unroll
    for (int p = 0; p < 16; ++p) {   // x tile: 2048 f4
        int i = tid + p * 128;
        int r = i >> 5, k4 = i & 31;
        int gr = row0 + r; if (gr > N_NODES - 1) gr = N_NODES - 1;
        xs4[r * 32 + (k4 ^ ((r >> 2) & 7))] = h24[gr * 32 + k4];
    }
    __syncthreads();

    float4 acc[4];
    #pragma unroll
    for (int i = 0; i < 4; ++i) acc[i] = make_float4(0.f, 0.f, 0.f, 0.f);
    const int sw = tr & 7;
    #pragma unroll 2
    for (int k4 = 0; k4 < 32; ++k4) {
        float4 w0 = ws4[(4 * k4 + 0) * 8 + tc];
        float4 w1 = ws4[(4 * k4 + 1) * 8 + tc];
        float4 w2 = ws4[(4 * k4 + 2) * 8 + tc];
        float4 w3 = ws4[(4 * k4 + 3) * 8 + tc];
        const int kk = k4 ^ sw;
        #pragma unroll
        for (int i = 0; i < 4; ++i) {
            float4 a = xs4[(4 * tr + i) * 32 + kk];
            fma4(acc[i], a, w0, w1, w2, w3);
        }
    }

    const float4 as4 = ((const float4*)a_src)[tc];
    const float4 ad4 = ((const float4*)a_dst)[tc];
    #pragma unroll
    for (int i = 0; i < 4; ++i) {
        int r = row0 + 4 * tr + i;
        if (r < N_NODES) {
            ((float4*)t2)[r * 8 + tc] = acc[i];
            float s = dot4(acc[i], as4);
            float d = dot4(acc[i], ad4);
            s += __shfl_xor(s, 1); s += __shfl_xor(s, 2); s += __shfl_xor(s, 4);
            d += __shfl_xor(d, 1); d += __shfl_xor(d, 2); d += __shfl_xor(d, 4);
            if (tc == 0) {
                al_src[r] = s;
                al_dst[r] = d;
            }
        }
    }
}

// ---------------- agg2: layer-2 gather + bias + log_softmax -> out ----------------
__global__ __launch_bounds__(64) void k_agg2(
    const float* __restrict__ t2, const float* __restrict__ al_src,
    const float* __restrict__ al_dst, const int* __restrict__ row_ptr,
    const int* __restrict__ csr_src, const float* __restrict__ b2,
    float* __restrict__ out)
{
    const int n = blockIdx.x;
    const int t = threadIdx.x;
    const int f = t & 31;
    const int half = t >> 5;
    const float alD = al_dst[n];
    float denom = 0.f, acc = 0.f;
    if (half == 0) {
        float e = leaky(al_src[n] + alD);
        float w = __expf(e);
        denom = w;
        acc = w * t2[n * 32 + f];
    }
    const int beg = row_ptr[n], end = row_ptr[n + 1];
    for (int j = beg + half; j < end; j += 2) {
        int s = csr_src[j];
        float e = leaky(al_src[s] + alD);
        float w = __expf(e);
        denom += w;
        acc = fmaf(w, t2[s * 32 + f], acc);
    }
    acc   += __shfl_xor(acc, 32);
    denom += __shfl_xor(denom, 32);
    float o = acc / denom + b2[f];
    float m = o;
    for (int off = 16; off; off >>= 1) m = fmaxf(m, __shfl_xor(m, off));
    float ex = __expf(o - m);
    float ssum = ex;
    for (int off = 16; off; off >>= 1) ssum += __shfl_xor(ssum, off);
    float res = (o - m) - __logf(ssum);
    if (half == 0) out[n * 32 + f] = res;
}

extern "C" void kernel_launch(void* const* d_in, const int* in_sizes, int n_in,
                              void* d_out, int out_size, void* d_ws, size_t ws_size,
                              hipStream_t stream) {
    const float* x      = (const float*)d_in[0];
    const int*   src    = (const int*)d_in[1];
    const int*   dst    = (const int*)d_in[2];
    const float* W1     = (const float*)d_in[3];
    const float* a_src1 = (const float*)d_in[4];
    const float* a_dst1 = (const float*)d_in[5];
    const float* b1     = (const float*)d_in[6];
    const float* W2     = (const float*)d_in[7];
    const float* a_src2 = (const float*)d_in[8];
    const float* a_dst2 = (const float*)d_in[9];
    const float* b2     = (const float*)d_in[10];
    float* out = (float*)d_out;

    char* ws = (char*)d_ws;
    size_t off = 0;
    auto alloc = [&](size_t bytes) {
        void* p = ws + off;
        off += (bytes + 255) & ~(size_t)255;
        return p;
    };
    float* h1      = (float*)alloc((size_t)N_NODES * 128 * 4);
    float* h2      = (float*)alloc((size_t)N_NODES * 128 * 4);
    float* t2      = (float*)alloc((size_t)N_NODES * 32 * 4);
    float* alS1    = (float*)alloc((size_t)N_NODES * 8 * 4);
    float* alD1    = (float*)alloc((size_t)N_NODES * 8 * 4);
    float* alS2    = (float*)alloc((size_t)N_NODES * 4);
    float* alD2    = (float*)alloc((size_t)N_NODES * 4);
    int*   deg     = (int*)alloc((size_t)N_NODES * 4);
    int*   rowp    = (int*)alloc((size_t)(N_NODES + 1) * 4);
    int*   cursor  = (int*)alloc((size_t)N_NODES * 4);
    int*   csr     = (int*)alloc((size_t)N_EDGES * 4);
    int*   partial = (int*)alloc((size_t)SCAN_NBLK * 4);
    (void)ws_size; (void)in_sizes; (void)n_in; (void)out_size;

    const int row_tiles = (N_NODES + 63) / 64;   // 782

    hipMemsetAsync(deg, 0, (size_t)N_NODES * 4, stream);
    k_deg<<<(N_EDGES + 255) / 256, 256, 0, stream>>>(dst, deg);
    k_scan_part<<<SCAN_NBLK, 1024, 0, stream>>>(deg, partial);
    k_scan_apply<<<SCAN_NBLK, 1024, 0, stream>>>(deg, partial, rowp, cursor);
    k_scatter<<<(N_EDGES + 255) / 256, 256, 0, stream>>>(src, dst, cursor, csr);
    k_gemm1<<<row_tiles * 2, 256, 0, stream>>>(x, W1, a_src1, a_dst1, h1, alS1, alD1);
    k_agg1<<<N_NODES, 128, 0, stream>>>(h1, alS1, alD1, rowp, csr, b1, h2);
    k_gemm2<<<row_tiles, 128, 0, stream>>>(h2, W2, a_src2, a_dst2, t2, alS2, alD2);
    k_agg2<<<N_NODES, 64, 0, stream>>>(t2, alS2, alD2, rowp, csr, b2, out);
}

// Round 4
// 323.117 us; speedup vs baseline: 1.7035x; 1.0576x over previous
//
#include <hip/hip_runtime.h>

#define N_NODES   50000
#define N_EDGES   800000
#define NEG_SLOPE 0.2f
#define SCAN_NBLK 49          // ceil(50000/1024)

__device__ __forceinline__ float leaky(float x) {
    return x > 0.f ? x : x * NEG_SLOPE;
}

__device__ __forceinline__ unsigned short f2bf(float f) {   // RNE pack
    unsigned int u = __float_as_uint(f);
    unsigned int r = (u + 0x7FFFu + ((u >> 16) & 1u)) >> 16;
    return (unsigned short)r;
}

__device__ __forceinline__ float2 bf2f2(unsigned int p) {   // packed bf16x2 -> float2
    return make_float2(__uint_as_float(p << 16),
                       __uint_as_float(p & 0xFFFF0000u));
}

__device__ __forceinline__ void fma4(float4& acc, const float4 a,
                                     const float4 w0, const float4 w1,
                                     const float4 w2, const float4 w3) {
    acc.x = fmaf(a.x, w0.x, fmaf(a.y, w1.x, fmaf(a.z, w2.x, fmaf(a.w, w3.x, acc.x))));
    acc.y = fmaf(a.x, w0.y, fmaf(a.y, w1.y, fmaf(a.z, w2.y, fmaf(a.w, w3.y, acc.y))));
    acc.z = fmaf(a.x, w0.z, fmaf(a.y, w1.z, fmaf(a.z, w2.z, fmaf(a.w, w3.z, acc.z))));
    acc.w = fmaf(a.x, w0.w, fmaf(a.y, w1.w, fmaf(a.z, w2.w, fmaf(a.w, w3.w, acc.w))));
}

__device__ __forceinline__ float dot4(const float4 a, const float4 b) {
    return a.x * b.x + a.y * b.y + a.z * b.z + a.w * b.w;
}

// ---------------- CSR build ----------------
__global__ void k_deg(const int* __restrict__ dst, int* __restrict__ deg) {
    int i = blockIdx.x * blockDim.x + threadIdx.x;
    if (i < N_EDGES) atomicAdd(&deg[dst[i]], 1);
}

__global__ __launch_bounds__(1024) void k_scan_part(const int* __restrict__ deg,
                                                    int* __restrict__ partial) {
    __shared__ int red[1024];
    const int b = blockIdx.x, tid = threadIdx.x;
    const int idx = b * 1024 + tid;
    red[tid] = (idx < N_NODES) ? deg[idx] : 0;
    __syncthreads();
    for (int off = 512; off; off >>= 1) {
        if (tid < off) red[tid] += red[tid + off];
        __syncthreads();
    }
    if (tid == 0) partial[b] = red[0];
}

__global__ __launch_bounds__(1024) void k_scan_apply(const int* __restrict__ deg,
                                                     const int* __restrict__ partial,
                                                     int* __restrict__ row_ptr,
                                                     int* __restrict__ cursor) {
    __shared__ int sh[1024];
    __shared__ int psh[64];
    __shared__ int blockoff_sh;
    const int b = blockIdx.x, tid = threadIdx.x;
    if (tid < 64) psh[tid] = (tid < SCAN_NBLK) ? partial[tid] : 0;
    const int idx = b * 1024 + tid;
    const int v = (idx < N_NODES) ? deg[idx] : 0;
    sh[tid] = v;
    __syncthreads();
    if (tid == 0) {
        int s = 0;
        for (int i = 0; i < b; ++i) s += psh[i];
        blockoff_sh = s;
    }
    for (int off = 1; off < 1024; off <<= 1) {
        int add = (tid >= off) ? sh[tid - off] : 0;
        __syncthreads();
        sh[tid] += add;
        __syncthreads();
    }
    const int incl = sh[tid];
    const int base = blockoff_sh;
    if (idx < N_NODES) {
        int excl = base + incl - v;
        row_ptr[idx] = excl;
        cursor[idx]  = excl;
    }
    if (b == SCAN_NBLK - 1 && tid == 1023) row_ptr[N_NODES] = base + incl;
}

__global__ void k_scatter(const int* __restrict__ src, const int* __restrict__ dst,
                          int* __restrict__ cursor, int* __restrict__ csr_src) {
    int i = blockIdx.x * blockDim.x + threadIdx.x;
    if (i < N_EDGES) {
        int d = dst[i];
        int pos = atomicAdd(&cursor[d], 1);
        csr_src[pos] = src[i];
    }
}

// ---------------- GEMM1: h1(bf16) = x @ W1 (+ fused al_src/al_dst) ----------------
__global__ __launch_bounds__(256) void k_gemm1(
    const float* __restrict__ x, const float* __restrict__ W1,
    const float* __restrict__ a_src, const float* __restrict__ a_dst,
    unsigned short* __restrict__ h1b, float* __restrict__ al_src,
    float* __restrict__ al_dst)
{
    __shared__ float4 xs4[64 * 32];   // 32 KB, [r][k4 ^ ((r>>2)&7)]
    __shared__ float4 ws4[128 * 16];  // 32 KB, [k][c4]
    const int tid  = threadIdx.x;
    const int half = blockIdx.x & 1;
    const int row0 = (int)(blockIdx.x >> 1) * 64;
    const int tc   = tid & 15;
    const int tr   = tid >> 4;
    const float4* x4  = (const float4*)x;
    const float4* W14 = (const float4*)W1;

    #pragma unroll
    for (int p = 0; p < 8; ++p) {
        int i = tid + p * 256;
        int k = i >> 4, c4 = i & 15;
        ws4[k * 16 + c4] = W14[k * 32 + half * 16 + c4];
    }
    #pragma unroll
    for (int p = 0; p < 8; ++p) {
        int i = tid + p * 256;
        int r = i >> 5, k4 = i & 31;
        int gr = row0 + r; if (gr > N_NODES - 1) gr = N_NODES - 1;
        xs4[r * 32 + (k4 ^ ((r >> 2) & 7))] = x4[gr * 32 + k4];
    }
    __syncthreads();

    float4 acc[4];
    #pragma unroll
    for (int i = 0; i < 4; ++i) acc[i] = make_float4(0.f, 0.f, 0.f, 0.f);
    const int sw = tr & 7;
    #pragma unroll 2
    for (int k4 = 0; k4 < 32; ++k4) {
        float4 w0 = ws4[(4 * k4 + 0) * 16 + tc];
        float4 w1 = ws4[(4 * k4 + 1) * 16 + tc];
        float4 w2 = ws4[(4 * k4 + 2) * 16 + tc];
        float4 w3 = ws4[(4 * k4 + 3) * 16 + tc];
        const int kk = k4 ^ sw;
        #pragma unroll
        for (int i = 0; i < 4; ++i) {
            float4 a = xs4[(4 * tr + i) * 32 + kk];
            fma4(acc[i], a, w0, w1, w2, w3);
        }
    }

    const int c0   = half * 64 + 4 * tc;
    const int head = c0 >> 4;
    const float4 as4 = ((const float4*)a_src)[half * 16 + tc];
    const float4 ad4 = ((const float4*)a_dst)[half * 16 + tc];
    #pragma unroll
    for (int i = 0; i < 4; ++i) {
        int r = row0 + 4 * tr + i;
        if (r < N_NODES) {
            ((ushort4*)h1b)[r * 32 + half * 16 + tc] =
                make_ushort4(f2bf(acc[i].x), f2bf(acc[i].y),
                             f2bf(acc[i].z), f2bf(acc[i].w));
            float s = dot4(acc[i], as4);
            float d = dot4(acc[i], ad4);
            s += __shfl_xor(s, 1); s += __shfl_xor(s, 2);
            d += __shfl_xor(d, 1); d += __shfl_xor(d, 2);
            if ((tc & 3) == 0) {
                al_src[r * 8 + head] = s;
                al_dst[r * 8 + head] = d;
            }
        }
    }
}

// ---------------- agg1: one wave per node, bf16 gather, shuffle weights ----------------
// lane l owns feats (2l, 2l+1) -> head l>>3. Chunks of 8 edges; lane l computes
// the weight for (edge l>>3, head l&7); consumers fetch via __shfl.
__global__ __launch_bounds__(256) void k_agg1(
    const unsigned short* __restrict__ h1b, const float* __restrict__ al_src,
    const float* __restrict__ al_dst, const int* __restrict__ row_ptr,
    const int* __restrict__ csr_src, const float* __restrict__ b1,
    float* __restrict__ h2)
{
    const int n = blockIdx.x * 4 + (threadIdx.x >> 6);
    const int l = threadIdx.x & 63;
    const unsigned int* h1u = (const unsigned int*)h1b;   // bf16x2 words

    const int   h    = l >> 3;
    const float alD  = al_dst[n * 8 + h];                 // head of MY feats
    const float alDw = __shfl(alD, (l & 7) * 8);          // head of MY WEIGHT slot

    // self loop
    float w0 = __expf(leaky(al_src[n * 8 + h] + alD));
    float denom = w0;
    float2 hv = bf2f2(h1u[n * 64 + l]);
    float2 acc = make_float2(w0 * hv.x, w0 * hv.y);

    const int beg = row_ptr[n], end = row_ptr[n + 1];
    const int e_w = l >> 3, h_w = l & 7;
    for (int j0 = beg; j0 < end; j0 += 8) {
        const int nE = min(8, end - j0);
        int s_w = 0;
        if (e_w < nE) s_w = csr_src[j0 + e_w];
        float w = __expf(leaky(al_src[s_w * 8 + h_w] + alDw));
        #pragma unroll 4
        for (int e = 0; e < nE; ++e) {
            float we = __shfl(w,   e * 8 + h);
            int   se = __shfl(s_w, e * 8);
            float2 v = bf2f2(h1u[se * 64 + l]);
            denom += we;
            acc.x = fmaf(we, v.x, acc.x);
            acc.y = fmaf(we, v.y, acc.y);
        }
    }
    const float2 b2v = ((const float2*)b1)[l];
    float ox = acc.x / denom + b2v.x;
    float oy = acc.y / denom + b2v.y;
    ox = ox > 0.f ? ox : expm1f(ox);
    oy = oy > 0.f ? oy : expm1f(oy);
    ((float2*)h2)[n * 64 + l] = make_float2(ox, oy);
}

// ---------------- GEMM2: t2(bf16) = h2 @ W2 (+ fused al2) ----------------
__global__ __launch_bounds__(128) void k_gemm2(
    const float* __restrict__ h2, const float* __restrict__ W2,
    const float* __restrict__ a_src, const float* __restrict__ a_dst,
    unsigned short* __restrict__ t2b, float* __restrict__ al_src,
    float* __restrict__ al_dst)
{
    __shared__ float4 xs4[64 * 32];  // 32 KB (swizzled)
    __shared__ float4 ws4[128 * 8];  // 16 KB
    const int tid  = threadIdx.x;
    const int row0 = (int)blockIdx.x * 64;
    const int tc   = tid & 7;
    const int tr   = tid >> 3;
    const float4* h24 = (const float4*)h2;
    const float4* W24 = (const float4*)W2;

    #pragma unroll
    for (int p = 0; p < 8; ++p) {
        int i = tid + p * 128;
        ws4[i] = W24[i];
    }
    #pragma unroll
    for (int p = 0; p < 16; ++p) {
        int i = tid + p * 128;
        int r = i >> 5, k4 = i & 31;
        int gr = row0 + r; if (gr > N_NODES - 1) gr = N_NODES - 1;
        xs4[r * 32 + (k4 ^ ((r >> 2) & 7))] = h24[gr * 32 + k4];
    }
    __syncthreads();

    float4 acc[4];
    #pragma unroll
    for (int i = 0; i < 4; ++i) acc[i] = make_float4(0.f, 0.f, 0.f, 0.f);
    const int sw = tr & 7;
    #pragma unroll 2
    for (int k4 = 0; k4 < 32; ++k4) {
        float4 w0 = ws4[(4 * k4 + 0) * 8 + tc];
        float4 w1 = ws4[(4 * k4 + 1) * 8 + tc];
        float4 w2 = ws4[(4 * k4 + 2) * 8 + tc];
        float4 w3 = ws4[(4 * k4 + 3) * 8 + tc];
        const int kk = k4 ^ sw;
        #pragma unroll
        for (int i = 0; i < 4; ++i) {
            float4 a = xs4[(4 * tr + i) * 32 + kk];
            fma4(acc[i], a, w0, w1, w2, w3);
        }
    }

    const float4 as4 = ((const float4*)a_src)[tc];
    const float4 ad4 = ((const float4*)a_dst)[tc];
    #pragma unroll
    for (int i = 0; i < 4; ++i) {
        int r = row0 + 4 * tr + i;
        if (r < N_NODES) {
            ((ushort4*)t2b)[r * 8 + tc] =
                make_ushort4(f2bf(acc[i].x), f2bf(acc[i].y),
                             f2bf(acc[i].z), f2bf(acc[i].w));
            float s = dot4(acc[i], as4);
            float d = dot4(acc[i], ad4);
            s += __shfl_xor(s, 1); s += __shfl_xor(s, 2); s += __shfl_xor(s, 4);
            d += __shfl_xor(d, 1); d += __shfl_xor(d, 2); d += __shfl_xor(d, 4);
            if (tc == 0) {
                al_src[r] = s;
                al_dst[r] = d;
            }
        }
    }
}

// ---------------- agg2: one wave per node, 4 edge slots x 16 lanes ----------------
__global__ __launch_bounds__(256) void k_agg2(
    const unsigned short* __restrict__ t2b, const float* __restrict__ al_src,
    const float* __restrict__ al_dst, const int* __restrict__ row_ptr,
    const int* __restrict__ csr_src, const float* __restrict__ b2,
    float* __restrict__ out)
{
    const int n = blockIdx.x * 4 + (threadIdx.x >> 6);
    const int l = threadIdx.x & 63;
    const int slot = l >> 4;          // 4 edge slots
    const int f2   = l & 15;          // feats (2*f2, 2*f2+1)
    const unsigned int* t2u = (const unsigned int*)t2b;

    const float alD = al_dst[n];
    float denom = 0.f;
    float2 acc = make_float2(0.f, 0.f);
    if (slot == 0) {                  // self loop
        float w = __expf(leaky(al_src[n] + alD));
        float2 v = bf2f2(t2u[n * 16 + f2]);
        denom = w;
        acc = make_float2(w * v.x, w * v.y);
    }
    const int beg = row_ptr[n], end = row_ptr[n + 1];
    for (int j0 = beg; j0 < end; j0 += 4) {
        const int nE = end - j0;
        if (slot < nE) {
            int s = csr_src[j0 + slot];
            float w = __expf(leaky(al_src[s] + alD));
            float2 v = bf2f2(t2u[s * 16 + f2]);
            denom += w;
            acc.x = fmaf(w, v.x, acc.x);
            acc.y = fmaf(w, v.y, acc.y);
        }
    }
    // sum the 4 slots
    acc.x += __shfl_xor(acc.x, 16); acc.y += __shfl_xor(acc.y, 16);
    denom += __shfl_xor(denom, 16);
    acc.x += __shfl_xor(acc.x, 32); acc.y += __shfl_xor(acc.y, 32);
    denom += __shfl_xor(denom, 32);

    const float2 bb = ((const float2*)b2)[f2];
    float ox = acc.x / denom + bb.x;
    float oy = acc.y / denom + bb.y;
    // log_softmax over 32 classes (16 lanes x 2 feats)
    float m = fmaxf(ox, oy);
    for (int off = 8; off; off >>= 1) m = fmaxf(m, __shfl_xor(m, off));
    float ssum = __expf(ox - m) + __expf(oy - m);
    for (int off = 8; off; off >>= 1) ssum += __shfl_xor(ssum, off);
    float lg = __logf(ssum);
    if (l < 16)
        ((float2*)out)[n * 16 + f2] = make_float2(ox - m - lg, oy - m - lg);
}

extern "C" void kernel_launch(void* const* d_in, const int* in_sizes, int n_in,
                              void* d_out, int out_size, void* d_ws, size_t ws_size,
                              hipStream_t stream) {
    const float* x      = (const float*)d_in[0];
    const int*   src    = (const int*)d_in[1];
    const int*   dst    = (const int*)d_in[2];
    const float* W1     = (const float*)d_in[3];
    const float* a_src1 = (const float*)d_in[4];
    const float* a_dst1 = (const float*)d_in[5];
    const float* b1     = (const float*)d_in[6];
    const float* W2     = (const float*)d_in[7];
    const float* a_src2 = (const float*)d_in[8];
    const float* a_dst2 = (const float*)d_in[9];
    const float* b2     = (const float*)d_in[10];
    float* out = (float*)d_out;

    char* ws = (char*)d_ws;
    size_t off = 0;
    auto alloc = [&](size_t bytes) {
        void* p = ws + off;
        off += (bytes + 255) & ~(size_t)255;
        return p;
    };
    unsigned short* h1b = (unsigned short*)alloc((size_t)N_NODES * 128 * 2);
    float*          h2  = (float*)alloc((size_t)N_NODES * 128 * 4);
    unsigned short* t2b = (unsigned short*)alloc((size_t)N_NODES * 32 * 2);
    float* alS1    = (float*)alloc((size_t)N_NODES * 8 * 4);
    float* alD1    = (float*)alloc((size_t)N_NODES * 8 * 4);
    float* alS2    = (float*)alloc((size_t)N_NODES * 4);
    float* alD2    = (float*)alloc((size_t)N_NODES * 4);
    int*   deg     = (int*)alloc((size_t)N_NODES * 4);
    int*   rowp    = (int*)alloc((size_t)(N_NODES + 1) * 4);
    int*   cursor  = (int*)alloc((size_t)N_NODES * 4);
    int*   csr     = (int*)alloc((size_t)N_EDGES * 4);
    int*   partial = (int*)alloc((size_t)SCAN_NBLK * 4);
    (void)ws_size; (void)in_sizes; (void)n_in; (void)out_size;

    const int row_tiles = (N_NODES + 63) / 64;   // 782

    hipMemsetAsync(deg, 0, (size_t)N_NODES * 4, stream);
    k_deg<<<(N_EDGES + 255) / 256, 256, 0, stream>>>(dst, deg);
    k_scan_part<<<SCAN_NBLK, 1024, 0, stream>>>(deg, partial);
    k_scan_apply<<<SCAN_NBLK, 1024, 0, stream>>>(deg, partial, rowp, cursor);
    k_scatter<<<(N_EDGES + 255) / 256, 256, 0, stream>>>(src, dst, cursor, csr);
    k_gemm1<<<row_tiles * 2, 256, 0, stream>>>(x, W1, a_src1, a_dst1, h1b, alS1, alD1);
    k_agg1<<<N_NODES / 4, 256, 0, stream>>>(h1b, alS1, alD1, rowp, csr, b1, h2);
    k_gemm2<<<row_tiles, 128, 0, stream>>>(h2, W2, a_src2, a_dst2, t2b, alS2, alD2);
    k_agg2<<<N_NODES / 4, 256, 0, stream>>>(t2b, alS2, alD2, rowp, csr, b2, out);
}

// Round 5
// 309.457 us; speedup vs baseline: 1.7786x; 1.0441x over previous
//
#include <hip/hip_runtime.h>

#define N_NODES   50000
#define N_EDGES   800000
#define NEG_SLOPE 0.2f
#define SCAN_NBLK 49          // ceil(50000/1024)

__device__ __forceinline__ float leaky(float x) {
    return x > 0.f ? x : x * NEG_SLOPE;
}

__device__ __forceinline__ unsigned short f2bf(float f) {   // RNE pack
    unsigned int u = __float_as_uint(f);
    unsigned int r = (u + 0x7FFFu + ((u >> 16) & 1u)) >> 16;
    return (unsigned short)r;
}

__device__ __forceinline__ float2 bf2f2(unsigned int p) {   // packed bf16x2 -> float2
    return make_float2(__uint_as_float(p << 16),
                       __uint_as_float(p & 0xFFFF0000u));
}

__device__ __forceinline__ void fma4(float4& acc, const float4 a,
                                     const float4 w0, const float4 w1,
                                     const float4 w2, const float4 w3) {
    acc.x = fmaf(a.x, w0.x, fmaf(a.y, w1.x, fmaf(a.z, w2.x, fmaf(a.w, w3.x, acc.x))));
    acc.y = fmaf(a.x, w0.y, fmaf(a.y, w1.y, fmaf(a.z, w2.y, fmaf(a.w, w3.y, acc.y))));
    acc.z = fmaf(a.x, w0.z, fmaf(a.y, w1.z, fmaf(a.z, w2.z, fmaf(a.w, w3.z, acc.z))));
    acc.w = fmaf(a.x, w0.w, fmaf(a.y, w1.w, fmaf(a.z, w2.w, fmaf(a.w, w3.w, acc.w))));
}

__device__ __forceinline__ float dot4(const float4 a, const float4 b) {
    return a.x * b.x + a.y * b.y + a.z * b.z + a.w * b.w;
}

// ---------------- CSR build ----------------
__global__ void k_deg(const int* __restrict__ dst, int* __restrict__ deg) {
    int i = blockIdx.x * blockDim.x + threadIdx.x;
    if (i < N_EDGES) atomicAdd(&deg[dst[i]], 1);
}

__global__ __launch_bounds__(1024) void k_scan_part(const int* __restrict__ deg,
                                                    int* __restrict__ partial) {
    __shared__ int red[1024];
    const int b = blockIdx.x, tid = threadIdx.x;
    const int idx = b * 1024 + tid;
    red[tid] = (idx < N_NODES) ? deg[idx] : 0;
    __syncthreads();
    for (int off = 512; off; off >>= 1) {
        if (tid < off) red[tid] += red[tid + off];
        __syncthreads();
    }
    if (tid == 0) partial[b] = red[0];
}

__global__ __launch_bounds__(1024) void k_scan_apply(const int* __restrict__ deg,
                                                     const int* __restrict__ partial,
                                                     int* __restrict__ row_ptr,
                                                     int* __restrict__ cursor) {
    __shared__ int sh[1024];
    __shared__ int psh[64];
    __shared__ int blockoff_sh;
    const int b = blockIdx.x, tid = threadIdx.x;
    if (tid < 64) psh[tid] = (tid < SCAN_NBLK) ? partial[tid] : 0;
    const int idx = b * 1024 + tid;
    const int v = (idx < N_NODES) ? deg[idx] : 0;
    sh[tid] = v;
    __syncthreads();
    if (tid == 0) {
        int s = 0;
        for (int i = 0; i < b; ++i) s += psh[i];
        blockoff_sh = s;
    }
    for (int off = 1; off < 1024; off <<= 1) {
        int add = (tid >= off) ? sh[tid - off] : 0;
        __syncthreads();
        sh[tid] += add;
        __syncthreads();
    }
    const int incl = sh[tid];
    const int base = blockoff_sh;
    if (idx < N_NODES) {
        int excl = base + incl - v;
        row_ptr[idx] = excl;
        cursor[idx]  = excl;
    }
    if (b == SCAN_NBLK - 1 && tid == 1023) row_ptr[N_NODES] = base + incl;
}

__global__ void k_scatter(const int* __restrict__ src, const int* __restrict__ dst,
                          int* __restrict__ cursor, int* __restrict__ csr_src) {
    int i = blockIdx.x * blockDim.x + threadIdx.x;
    if (i < N_EDGES) {
        int d = dst[i];
        int pos = atomicAdd(&cursor[d], 1);
        csr_src[pos] = src[i];
    }
}

// ---------------- GEMM1: h1(bf16) = x @ W1 (+ fused al_src/al_dst) ----------------
__global__ __launch_bounds__(256) void k_gemm1(
    const float* __restrict__ x, const float* __restrict__ W1,
    const float* __restrict__ a_src, const float* __restrict__ a_dst,
    unsigned short* __restrict__ h1b, float* __restrict__ al_src,
    float* __restrict__ al_dst)
{
    __shared__ float4 xs4[64 * 32];   // 32 KB, [r][k4 ^ ((r>>2)&7)]
    __shared__ float4 ws4[128 * 16];  // 32 KB, [k][c4]
    const int tid  = threadIdx.x;
    const int half = blockIdx.x & 1;
    const int row0 = (int)(blockIdx.x >> 1) * 64;
    const int tc   = tid & 15;
    const int tr   = tid >> 4;
    const float4* x4  = (const float4*)x;
    const float4* W14 = (const float4*)W1;

    #pragma unroll
    for (int p = 0; p < 8; ++p) {
        int i = tid + p * 256;
        int k = i >> 4, c4 = i & 15;
        ws4[k * 16 + c4] = W14[k * 32 + half * 16 + c4];
    }
    #pragma unroll
    for (int p = 0; p < 8; ++p) {
        int i = tid + p * 256;
        int r = i >> 5, k4 = i & 31;
        int gr = row0 + r; if (gr > N_NODES - 1) gr = N_NODES - 1;
        xs4[r * 32 + (k4 ^ ((r >> 2) & 7))] = x4[gr * 32 + k4];
    }
    __syncthreads();

    float4 acc[4];
    #pragma unroll
    for (int i = 0; i < 4; ++i) acc[i] = make_float4(0.f, 0.f, 0.f, 0.f);
    const int sw = tr & 7;
    #pragma unroll 2
    for (int k4 = 0; k4 < 32; ++k4) {
        float4 w0 = ws4[(4 * k4 + 0) * 16 + tc];
        float4 w1 = ws4[(4 * k4 + 1) * 16 + tc];
        float4 w2 = ws4[(4 * k4 + 2) * 16 + tc];
        float4 w3 = ws4[(4 * k4 + 3) * 16 + tc];
        const int kk = k4 ^ sw;
        #pragma unroll
        for (int i = 0; i < 4; ++i) {
            float4 a = xs4[(4 * tr + i) * 32 + kk];
            fma4(acc[i], a, w0, w1, w2, w3);
        }
    }

    const int c0   = half * 64 + 4 * tc;
    const int head = c0 >> 4;
    const float4 as4 = ((const float4*)a_src)[half * 16 + tc];
    const float4 ad4 = ((const float4*)a_dst)[half * 16 + tc];
    #pragma unroll
    for (int i = 0; i < 4; ++i) {
        int r = row0 + 4 * tr + i;
        if (r < N_NODES) {
            ((ushort4*)h1b)[r * 32 + half * 16 + tc] =
                make_ushort4(f2bf(acc[i].x), f2bf(acc[i].y),
                             f2bf(acc[i].z), f2bf(acc[i].w));
            float s = dot4(acc[i], as4);
            float d = dot4(acc[i], ad4);
            s += __shfl_xor(s, 1); s += __shfl_xor(s, 2);
            d += __shfl_xor(d, 1); d += __shfl_xor(d, 2);
            if ((tc & 3) == 0) {
                al_src[r * 8 + head] = s;
                al_dst[r * 8 + head] = d;
            }
        }
    }
}

// ---------------- agg1: one wave per node, 4 edge slots x 16 lanes x 16B ----------------
// lane l: slot = l>>4 (edge stream, stride 4), f2 = l&15 -> feats 8*f2..8*f2+7
// (all within head f2>>1). Per edge: 16-lane uint4 gather of the bf16 row +
// per-lane weight from L2-resident al_src. No shuffles in the hot loop.
__global__ __launch_bounds__(256) void k_agg1(
    const unsigned short* __restrict__ h1b, const float* __restrict__ al_src,
    const float* __restrict__ al_dst, const int* __restrict__ row_ptr,
    const int* __restrict__ csr_src, const float* __restrict__ b1,
    float* __restrict__ h2)
{
    const int n = blockIdx.x * 4 + (threadIdx.x >> 6);
    const int l    = threadIdx.x & 63;
    const int slot = l >> 4;
    const int f2   = l & 15;
    const int head = f2 >> 1;
    const uint4* h1q = (const uint4*)h1b;    // 16 B = 8 bf16 feats

    const float alD = al_dst[n * 8 + head];
    float denom = 0.f;
    float acc[8];
    #pragma unroll
    for (int i = 0; i < 8; ++i) acc[i] = 0.f;

    if (slot == 0) {   // self loop
        float w = __expf(leaky(al_src[n * 8 + head] + alD));
        uint4 q = h1q[n * 16 + f2];
        float2 v0 = bf2f2(q.x), v1 = bf2f2(q.y), v2 = bf2f2(q.z), v3 = bf2f2(q.w);
        denom = w;
        acc[0] = w * v0.x; acc[1] = w * v0.y; acc[2] = w * v1.x; acc[3] = w * v1.y;
        acc[4] = w * v2.x; acc[5] = w * v2.y; acc[6] = w * v3.x; acc[7] = w * v3.y;
    }

    const int beg = row_ptr[n], end = row_ptr[n + 1];
    for (int j = beg + slot; j < end; j += 4) {
        int s = csr_src[j];
        float w = __expf(leaky(al_src[s * 8 + head] + alD));
        uint4 q = h1q[s * 16 + f2];
        denom += w;
        float2 v0 = bf2f2(q.x), v1 = bf2f2(q.y), v2 = bf2f2(q.z), v3 = bf2f2(q.w);
        acc[0] = fmaf(w, v0.x, acc[0]); acc[1] = fmaf(w, v0.y, acc[1]);
        acc[2] = fmaf(w, v1.x, acc[2]); acc[3] = fmaf(w, v1.y, acc[3]);
        acc[4] = fmaf(w, v2.x, acc[4]); acc[5] = fmaf(w, v2.y, acc[5]);
        acc[6] = fmaf(w, v3.x, acc[6]); acc[7] = fmaf(w, v3.y, acc[7]);
    }

    // reduce the 4 slots
    #pragma unroll
    for (int i = 0; i < 8; ++i) {
        acc[i] += __shfl_xor(acc[i], 16);
        acc[i] += __shfl_xor(acc[i], 32);
    }
    denom += __shfl_xor(denom, 16);
    denom += __shfl_xor(denom, 32);

    if (slot == 0) {
        const float4 bA = ((const float4*)b1)[f2 * 2];
        const float4 bB = ((const float4*)b1)[f2 * 2 + 1];
        float inv = 1.f / denom;
        float o[8];
        o[0] = acc[0] * inv + bA.x; o[1] = acc[1] * inv + bA.y;
        o[2] = acc[2] * inv + bA.z; o[3] = acc[3] * inv + bA.w;
        o[4] = acc[4] * inv + bB.x; o[5] = acc[5] * inv + bB.y;
        o[6] = acc[6] * inv + bB.z; o[7] = acc[7] * inv + bB.w;
        #pragma unroll
        for (int i = 0; i < 8; ++i) o[i] = o[i] > 0.f ? o[i] : expm1f(o[i]);
        ((float4*)h2)[n * 32 + f2 * 2]     = make_float4(o[0], o[1], o[2], o[3]);
        ((float4*)h2)[n * 32 + f2 * 2 + 1] = make_float4(o[4], o[5], o[6], o[7]);
    }
}

// ---------------- GEMM2: t2(bf16) = h2 @ W2 (+ fused al2) ----------------
__global__ __launch_bounds__(128) void k_gemm2(
    const float* __restrict__ h2, const float* __restrict__ W2,
    const float* __restrict__ a_src, const float* __restrict__ a_dst,
    unsigned short* __restrict__ t2b, float* __restrict__ al_src,
    float* __restrict__ al_dst)
{
    __shared__ float4 xs4[64 * 32];  // 32 KB (swizzled)
    __shared__ float4 ws4[128 * 8];  // 16 KB
    const int tid  = threadIdx.x;
    const int row0 = (int)blockIdx.x * 64;
    const int tc   = tid & 7;
    const int tr   = tid >> 3;
    const float4* h24 = (const float4*)h2;
    const float4* W24 = (const float4*)W2;

    #pragma unroll
    for (int p = 0; p < 8; ++p) {
        int i = tid + p * 128;
        ws4[i] = W24[i];
    }
    #pragma unroll
    for (int p = 0; p < 16; ++p) {
        int i = tid + p * 128;
        int r = i >> 5, k4 = i & 31;
        int gr = row0 + r; if (gr > N_NODES - 1) gr = N_NODES - 1;
        xs4[r * 32 + (k4 ^ ((r >> 2) & 7))] = h24[gr * 32 + k4];
    }
    __syncthreads();

    float4 acc[4];
    #pragma unroll
    for (int i = 0; i < 4; ++i) acc[i] = make_float4(0.f, 0.f, 0.f, 0.f);
    const int sw = tr & 7;
    #pragma unroll 2
    for (int k4 = 0; k4 < 32; ++k4) {
        float4 w0 = ws4[(4 * k4 + 0) * 8 + tc];
        float4 w1 = ws4[(4 * k4 + 1) * 8 + tc];
        float4 w2 = ws4[(4 * k4 + 2) * 8 + tc];
        float4 w3 = ws4[(4 * k4 + 3) * 8 + tc];
        const int kk = k4 ^ sw;
        #pragma unroll
        for (int i = 0; i < 4; ++i) {
            float4 a = xs4[(4 * tr + i) * 32 + kk];
            fma4(acc[i], a, w0, w1, w2, w3);
        }
    }

    const float4 as4 = ((const float4*)a_src)[tc];
    const float4 ad4 = ((const float4*)a_dst)[tc];
    #pragma unroll
    for (int i = 0; i < 4; ++i) {
        int r = row0 + 4 * tr + i;
        if (r < N_NODES) {
            ((ushort4*)t2b)[r * 8 + tc] =
                make_ushort4(f2bf(acc[i].x), f2bf(acc[i].y),
                             f2bf(acc[i].z), f2bf(acc[i].w));
            float s = dot4(acc[i], as4);
            float d = dot4(acc[i], ad4);
            s += __shfl_xor(s, 1); s += __shfl_xor(s, 2); s += __shfl_xor(s, 4);
            d += __shfl_xor(d, 1); d += __shfl_xor(d, 2); d += __shfl_xor(d, 4);
            if (tc == 0) {
                al_src[r] = s;
                al_dst[r] = d;
            }
        }
    }
}

// ---------------- agg2: one wave per node, 4 edge slots x 16 lanes ----------------
__global__ __launch_bounds__(256) void k_agg2(
    const unsigned short* __restrict__ t2b, const float* __restrict__ al_src,
    const float* __restrict__ al_dst, const int* __restrict__ row_ptr,
    const int* __restrict__ csr_src, const float* __restrict__ b2,
    float* __restrict__ out)
{
    const int n = blockIdx.x * 4 + (threadIdx.x >> 6);
    const int l = threadIdx.x & 63;
    const int slot = l >> 4;          // 4 edge slots
    const int f2   = l & 15;          // feats (2*f2, 2*f2+1)
    const unsigned int* t2u = (const unsigned int*)t2b;

    const float alD = al_dst[n];
    float denom = 0.f;
    float2 acc = make_float2(0.f, 0.f);
    if (slot == 0) {                  // self loop
        float w = __expf(leaky(al_src[n] + alD));
        float2 v = bf2f2(t2u[n * 16 + f2]);
        denom = w;
        acc = make_float2(w * v.x, w * v.y);
    }
    const int beg = row_ptr[n], end = row_ptr[n + 1];
    for (int j0 = beg; j0 < end; j0 += 4) {
        const int nE = end - j0;
        if (slot < nE) {
            int s = csr_src[j0 + slot];
            float w = __expf(leaky(al_src[s] + alD));
            float2 v = bf2f2(t2u[s * 16 + f2]);
            denom += w;
            acc.x = fmaf(w, v.x, acc.x);
            acc.y = fmaf(w, v.y, acc.y);
        }
    }
    // sum the 4 slots
    acc.x += __shfl_xor(acc.x, 16); acc.y += __shfl_xor(acc.y, 16);
    denom += __shfl_xor(denom, 16);
    acc.x += __shfl_xor(acc.x, 32); acc.y += __shfl_xor(acc.y, 32);
    denom += __shfl_xor(denom, 32);

    const float2 bb = ((const float2*)b2)[f2];
    float ox = acc.x / denom + bb.x;
    float oy = acc.y / denom + bb.y;
    // log_softmax over 32 classes (16 lanes x 2 feats)
    float m = fmaxf(ox, oy);
    for (int off = 8; off; off >>= 1) m = fmaxf(m, __shfl_xor(m, off));
    float ssum = __expf(ox - m) + __expf(oy - m);
    for (int off = 8; off; off >>= 1) ssum += __shfl_xor(ssum, off);
    float lg = __logf(ssum);
    if (l < 16)
        ((float2*)out)[n * 16 + f2] = make_float2(ox - m - lg, oy - m - lg);
}

extern "C" void kernel_launch(void* const* d_in, const int* in_sizes, int n_in,
                              void* d_out, int out_size, void* d_ws, size_t ws_size,
                              hipStream_t stream) {
    const float* x      = (const float*)d_in[0];
    const int*   src    = (const int*)d_in[1];
    const int*   dst    = (const int*)d_in[2];
    const float* W1     = (const float*)d_in[3];
    const float* a_src1 = (const float*)d_in[4];
    const float* a_dst1 = (const float*)d_in[5];
    const float* b1     = (const float*)d_in[6];
    const float* W2     = (const float*)d_in[7];
    const float* a_src2 = (const float*)d_in[8];
    const float* a_dst2 = (const float*)d_in[9];
    const float* b2     = (const float*)d_in[10];
    float* out = (float*)d_out;

    char* ws = (char*)d_ws;
    size_t off = 0;
    auto alloc = [&](size_t bytes) {
        void* p = ws + off;
        off += (bytes + 255) & ~(size_t)255;
        return p;
    };
    unsigned short* h1b = (unsigned short*)alloc((size_t)N_NODES * 128 * 2);
    float*          h2  = (float*)alloc((size_t)N_NODES * 128 * 4);
    unsigned short* t2b = (unsigned short*)alloc((size_t)N_NODES * 32 * 2);
    float* alS1    = (float*)alloc((size_t)N_NODES * 8 * 4);
    float* alD1    = (float*)alloc((size_t)N_NODES * 8 * 4);
    float* alS2    = (float*)alloc((size_t)N_NODES * 4);
    float* alD2    = (float*)alloc((size_t)N_NODES * 4);
    int*   deg     = (int*)alloc((size_t)N_NODES * 4);
    int*   rowp    = (int*)alloc((size_t)(N_NODES + 1) * 4);
    int*   cursor  = (int*)alloc((size_t)N_NODES * 4);
    int*   csr     = (int*)alloc((size_t)N_EDGES * 4);
    int*   partial = (int*)alloc((size_t)SCAN_NBLK * 4);
    (void)ws_size; (void)in_sizes; (void)n_in; (void)out_size;

    const int row_tiles = (N_NODES + 63) / 64;   // 782

    hipMemsetAsync(deg, 0, (size_t)N_NODES * 4, stream);
    k_deg<<<(N_EDGES + 255) / 256, 256, 0, stream>>>(dst, deg);
    k_scan_part<<<SCAN_NBLK, 1024, 0, stream>>>(deg, partial);
    k_scan_apply<<<SCAN_NBLK, 1024, 0, stream>>>(deg, partial, rowp, cursor);
    k_scatter<<<(N_EDGES + 255) / 256, 256, 0, stream>>>(src, dst, cursor, csr);
    k_gemm1<<<row_tiles * 2, 256, 0, stream>>>(x, W1, a_src1, a_dst1, h1b, alS1, alD1);
    k_agg1<<<N_NODES / 4, 256, 0, stream>>>(h1b, alS1, alD1, rowp, csr, b1, h2);
    k_gemm2<<<row_tiles, 128, 0, stream>>>(h2, W2, a_src2, a_dst2, t2b, alS2, alD2);
    k_agg2<<<N_NODES / 4, 256, 0, stream>>>(t2b, alS2, alD2, rowp, csr, b2, out);
}

// Round 6
// 243.057 us; speedup vs baseline: 2.2645x; 1.2732x over previous
//
#include <hip/hip_runtime.h>

#define N_NODES   50000
#define N_EDGES   800000
#define NEG_SLOPE 0.2f
#define NBKT      256          // coarse buckets
#define NPB       196          // nodes per bucket (196*256 = 50176 >= 50000)
#define EPB       3125         // edges per hist/binscatter block (800000/256)

__device__ __forceinline__ float leaky(float x) {
    return x > 0.f ? x : x * NEG_SLOPE;
}

__device__ __forceinline__ unsigned short f2bf(float f) {   // RNE pack
    unsigned int u = __float_as_uint(f);
    unsigned int r = (u + 0x7FFFu + ((u >> 16) & 1u)) >> 16;
    return (unsigned short)r;
}

__device__ __forceinline__ float2 bf2f2(unsigned int p) {   // packed bf16x2 -> float2
    return make_float2(__uint_as_float(p << 16),
                       __uint_as_float(p & 0xFFFF0000u));
}

__device__ __forceinline__ void fma4(float4& acc, const float4 a,
                                     const float4 w0, const float4 w1,
                                     const float4 w2, const float4 w3) {
    acc.x = fmaf(a.x, w0.x, fmaf(a.y, w1.x, fmaf(a.z, w2.x, fmaf(a.w, w3.x, acc.x))));
    acc.y = fmaf(a.x, w0.y, fmaf(a.y, w1.y, fmaf(a.z, w2.y, fmaf(a.w, w3.y, acc.y))));
    acc.z = fmaf(a.x, w0.z, fmaf(a.y, w1.z, fmaf(a.z, w2.z, fmaf(a.w, w3.z, acc.z))));
    acc.w = fmaf(a.x, w0.w, fmaf(a.y, w1.w, fmaf(a.z, w2.w, fmaf(a.w, w3.w, acc.w))));
}

__device__ __forceinline__ float dot4(const float4 a, const float4 b) {
    return a.x * b.x + a.y * b.y + a.z * b.z + a.w * b.w;
}

// ---------------- CSR build: two-level counting sort ----------------
// pass 1: per-block LDS histogram of coarse bucket (dst/NPB), bucket-major out
__global__ __launch_bounds__(256) void k_hist(const int* __restrict__ dst,
                                              int* __restrict__ hist_g) {
    __shared__ int h[NBKT];
    const int tid = threadIdx.x, blk = blockIdx.x;
    h[tid] = 0;
    __syncthreads();
    const int e0 = blk * EPB;
    for (int j = e0 + tid; j < e0 + EPB; j += 256)
        atomicAdd(&h[dst[j] / NPB], 1);
    __syncthreads();
    hist_g[tid * NBKT + blk] = h[tid];       // [bucket][block]
}

// scan 65536 entries, 2-pass: A = per-block sums, B = apply (exclusive)
__global__ __launch_bounds__(1024) void k_scanA(const int* __restrict__ hist_g,
                                                int* __restrict__ partial) {
    __shared__ int red[1024];
    const int tid = threadIdx.x;
    red[tid] = hist_g[blockIdx.x * 1024 + tid];
    __syncthreads();
    for (int off = 512; off; off >>= 1) {
        if (tid < off) red[tid] += red[tid + off];
        __syncthreads();
    }
    if (tid == 0) partial[blockIdx.x] = red[0];
}

__global__ __launch_bounds__(1024) void k_scanB(const int* __restrict__ hist_g,
                                                const int* __restrict__ partial,
                                                int* __restrict__ offs) {
    __shared__ int sh[1024];
    __shared__ int blockoff_sh;
    const int b = blockIdx.x, tid = threadIdx.x;
    const int idx = b * 1024 + tid;
    const int v = hist_g[idx];
    sh[tid] = v;
    __syncthreads();
    if (tid == 0) {
        int s = 0;
        for (int i = 0; i < b; ++i) s += partial[i];
        blockoff_sh = s;
    }
    for (int off = 1; off < 1024; off <<= 1) {
        int add = (tid >= off) ? sh[tid - off] : 0;
        __syncthreads();
        sh[tid] += add;
        __syncthreads();
    }
    offs[idx] = blockoff_sh + sh[tid] - v;   // exclusive
}

// pass 2: scatter packed (src | dstlocal<<18) into per-(bucket,block) runs
__global__ __launch_bounds__(256) void k_binscatter(const int* __restrict__ src,
                                                    const int* __restrict__ dst,
                                                    const int* __restrict__ offs,
                                                    unsigned int* __restrict__ binned) {
    __shared__ int cur[NBKT];
    const int tid = threadIdx.x, blk = blockIdx.x;
    cur[tid] = offs[tid * NBKT + blk];
    __syncthreads();
    const int e0 = blk * EPB;
    for (int j = e0 + tid; j < e0 + EPB; j += 256) {
        int d   = dst[j];
        int bkt = d / NPB;
        int dl  = d - bkt * NPB;
        int pos = atomicAdd(&cur[bkt], 1);
        binned[pos] = (unsigned int)src[j] | ((unsigned int)dl << 18);
    }
}

// pass 3: one block per bucket -> row_ptr + final csr (single-XCD locality)
__global__ __launch_bounds__(256) void k_csr_fine(const unsigned int* __restrict__ binned,
                                                  const int* __restrict__ offs,
                                                  int* __restrict__ row_ptr,
                                                  int* __restrict__ csr) {
    __shared__ int cnt[256];
    __shared__ int scan[256];
    __shared__ int cur[256];
    const int b = blockIdx.x, tid = threadIdx.x;
    const int start = offs[b * NBKT];
    const int end   = (b == NBKT - 1) ? N_EDGES : offs[(b + 1) * NBKT];
    cnt[tid] = 0;
    __syncthreads();
    for (int j = start + tid; j < end; j += 256)
        atomicAdd(&cnt[(binned[j] >> 18) & 255], 1);
    __syncthreads();
    const int v = cnt[tid];
    scan[tid] = v;
    __syncthreads();
    for (int off = 1; off < 256; off <<= 1) {
        int add = (tid >= off) ? scan[tid - off] : 0;
        __syncthreads();
        scan[tid] += add;
        __syncthreads();
    }
    const int excl = scan[tid] - v;
    cur[tid] = excl;
    const int node = b * NPB + tid;
    if (tid < NPB && node < N_NODES) row_ptr[node] = start + excl;
    if (b == NBKT - 1 && tid == 0)   row_ptr[N_NODES] = N_EDGES;
    __syncthreads();
    for (int j = start + tid; j < end; j += 256) {
        unsigned int p = binned[j];
        int dl  = (p >> 18) & 255;
        int pos = start + atomicAdd(&cur[dl], 1);
        csr[pos] = (int)(p & 0x3FFFFu);
    }
}

// ---------------- GEMM1: h1(bf16) = x @ W1 (+ fused al_src/al_dst) ----------------
__global__ __launch_bounds__(256) void k_gemm1(
    const float* __restrict__ x, const float* __restrict__ W1,
    const float* __restrict__ a_src, const float* __restrict__ a_dst,
    unsigned short* __restrict__ h1b, float* __restrict__ al_src,
    float* __restrict__ al_dst)
{
    __shared__ float4 xs4[64 * 32];   // 32 KB, [r][k4 ^ ((r>>2)&7)]
    __shared__ float4 ws4[128 * 16];  // 32 KB, [k][c4]
    const int tid  = threadIdx.x;
    const int half = blockIdx.x & 1;
    const int row0 = (int)(blockIdx.x >> 1) * 64;
    const int tc   = tid & 15;
    const int tr   = tid >> 4;
    const float4* x4  = (const float4*)x;
    const float4* W14 = (const float4*)W1;

    #pragma unroll
    for (int p = 0; p < 8; ++p) {
        int i = tid + p * 256;
        int k = i >> 4, c4 = i & 15;
        ws4[k * 16 + c4] = W14[k * 32 + half * 16 + c4];
    }
    #pragma unroll
    for (int p = 0; p < 8; ++p) {
        int i = tid + p * 256;
        int r = i >> 5, k4 = i & 31;
        int gr = row0 + r; if (gr > N_NODES - 1) gr = N_NODES - 1;
        xs4[r * 32 + (k4 ^ ((r >> 2) & 7))] = x4[gr * 32 + k4];
    }
    __syncthreads();

    float4 acc[4];
    #pragma unroll
    for (int i = 0; i < 4; ++i) acc[i] = make_float4(0.f, 0.f, 0.f, 0.f);
    const int sw = tr & 7;
    #pragma unroll 2
    for (int k4 = 0; k4 < 32; ++k4) {
        float4 w0 = ws4[(4 * k4 + 0) * 16 + tc];
        float4 w1 = ws4[(4 * k4 + 1) * 16 + tc];
        float4 w2 = ws4[(4 * k4 + 2) * 16 + tc];
        float4 w3 = ws4[(4 * k4 + 3) * 16 + tc];
        const int kk = k4 ^ sw;
        #pragma unroll
        for (int i = 0; i < 4; ++i) {
            float4 a = xs4[(4 * tr + i) * 32 + kk];
            fma4(acc[i], a, w0, w1, w2, w3);
        }
    }

    const int c0   = half * 64 + 4 * tc;
    const int head = c0 >> 4;
    const float4 as4 = ((const float4*)a_src)[half * 16 + tc];
    const float4 ad4 = ((const float4*)a_dst)[half * 16 + tc];
    #pragma unroll
    for (int i = 0; i < 4; ++i) {
        int r = row0 + 4 * tr + i;
        if (r < N_NODES) {
            ((ushort4*)h1b)[r * 32 + half * 16 + tc] =
                make_ushort4(f2bf(acc[i].x), f2bf(acc[i].y),
                             f2bf(acc[i].z), f2bf(acc[i].w));
            float s = dot4(acc[i], as4);
            float d = dot4(acc[i], ad4);
            s += __shfl_xor(s, 1); s += __shfl_xor(s, 2);
            d += __shfl_xor(d, 1); d += __shfl_xor(d, 2);
            if ((tc & 3) == 0) {
                al_src[r * 8 + head] = s;
                al_dst[r * 8 + head] = d;
            }
        }
    }
}

// ---------------- agg1: one wave per node, 4 edge slots x 16 lanes x 16B ----------------
__global__ __launch_bounds__(256) void k_agg1(
    const unsigned short* __restrict__ h1b, const float* __restrict__ al_src,
    const float* __restrict__ al_dst, const int* __restrict__ row_ptr,
    const int* __restrict__ csr_src, const float* __restrict__ b1,
    float* __restrict__ h2)
{
    const int n = blockIdx.x * 4 + (threadIdx.x >> 6);
    const int l    = threadIdx.x & 63;
    const int slot = l >> 4;
    const int f2   = l & 15;
    const int head = f2 >> 1;
    const uint4* h1q = (const uint4*)h1b;    // 16 B = 8 bf16 feats

    const float alD = al_dst[n * 8 + head];
    float denom = 0.f;
    float acc[8];
    #pragma unroll
    for (int i = 0; i < 8; ++i) acc[i] = 0.f;

    if (slot == 0) {   // self loop
        float w = __expf(leaky(al_src[n * 8 + head] + alD));
        uint4 q = h1q[n * 16 + f2];
        float2 v0 = bf2f2(q.x), v1 = bf2f2(q.y), v2 = bf2f2(q.z), v3 = bf2f2(q.w);
        denom = w;
        acc[0] = w * v0.x; acc[1] = w * v0.y; acc[2] = w * v1.x; acc[3] = w * v1.y;
        acc[4] = w * v2.x; acc[5] = w * v2.y; acc[6] = w * v3.x; acc[7] = w * v3.y;
    }

    const int beg = row_ptr[n], end = row_ptr[n + 1];
    for (int j = beg + slot; j < end; j += 4) {
        int s = csr_src[j];
        float w = __expf(leaky(al_src[s * 8 + head] + alD));
        uint4 q = h1q[s * 16 + f2];
        denom += w;
        float2 v0 = bf2f2(q.x), v1 = bf2f2(q.y), v2 = bf2f2(q.z), v3 = bf2f2(q.w);
        acc[0] = fmaf(w, v0.x, acc[0]); acc[1] = fmaf(w, v0.y, acc[1]);
        acc[2] = fmaf(w, v1.x, acc[2]); acc[3] = fmaf(w, v1.y, acc[3]);
        acc[4] = fmaf(w, v2.x, acc[4]); acc[5] = fmaf(w, v2.y, acc[5]);
        acc[6] = fmaf(w, v3.x, acc[6]); acc[7] = fmaf(w, v3.y, acc[7]);
    }

    #pragma unroll
    for (int i = 0; i < 8; ++i) {
        acc[i] += __shfl_xor(acc[i], 16);
        acc[i] += __shfl_xor(acc[i], 32);
    }
    denom += __shfl_xor(denom, 16);
    denom += __shfl_xor(denom, 32);

    if (slot == 0) {
        const float4 bA = ((const float4*)b1)[f2 * 2];
        const float4 bB = ((const float4*)b1)[f2 * 2 + 1];
        float inv = 1.f / denom;
        float o[8];
        o[0] = acc[0] * inv + bA.x; o[1] = acc[1] * inv + bA.y;
        o[2] = acc[2] * inv + bA.z; o[3] = acc[3] * inv + bA.w;
        o[4] = acc[4] * inv + bB.x; o[5] = acc[5] * inv + bB.y;
        o[6] = acc[6] * inv + bB.z; o[7] = acc[7] * inv + bB.w;
        #pragma unroll
        for (int i = 0; i < 8; ++i) o[i] = o[i] > 0.f ? o[i] : expm1f(o[i]);
        ((float4*)h2)[n * 32 + f2 * 2]     = make_float4(o[0], o[1], o[2], o[3]);
        ((float4*)h2)[n * 32 + f2 * 2 + 1] = make_float4(o[4], o[5], o[6], o[7]);
    }
}

// ---------------- GEMM2: t2(bf16) = h2 @ W2 (+ fused al2) ----------------
__global__ __launch_bounds__(128) void k_gemm2(
    const float* __restrict__ h2, const float* __restrict__ W2,
    const float* __restrict__ a_src, const float* __restrict__ a_dst,
    unsigned short* __restrict__ t2b, float* __restrict__ al_src,
    float* __restrict__ al_dst)
{
    __shared__ float4 xs4[64 * 32];  // 32 KB (swizzled)
    __shared__ float4 ws4[128 * 8];  // 16 KB
    const int tid  = threadIdx.x;
    const int row0 = (int)blockIdx.x * 64;
    const int tc   = tid & 7;
    const int tr   = tid >> 3;
    const float4* h24 = (const float4*)h2;
    const float4* W24 = (const float4*)W2;

    #pragma unroll
    for (int p = 0; p < 8; ++p) {
        int i = tid + p * 128;
        ws4[i] = W24[i];
    }
    #pragma unroll
    for (int p = 0; p < 16; ++p) {
        int i = tid + p * 128;
        int r = i >> 5, k4 = i & 31;
        int gr = row0 + r; if (gr > N_NODES - 1) gr = N_NODES - 1;
        xs4[r * 32 + (k4 ^ ((r >> 2) & 7))] = h24[gr * 32 + k4];
    }
    __syncthreads();

    float4 acc[4];
    #pragma unroll
    for (int i = 0; i < 4; ++i) acc[i] = make_float4(0.f, 0.f, 0.f, 0.f);
    const int sw = tr & 7;
    #pragma unroll 2
    for (int k4 = 0; k4 < 32; ++k4) {
        float4 w0 = ws4[(4 * k4 + 0) * 8 + tc];
        float4 w1 = ws4[(4 * k4 + 1) * 8 + tc];
        float4 w2 = ws4[(4 * k4 + 2) * 8 + tc];
        float4 w3 = ws4[(4 * k4 + 3) * 8 + tc];
        const int kk = k4 ^ sw;
        #pragma unroll
        for (int i = 0; i < 4; ++i) {
            float4 a = xs4[(4 * tr + i) * 32 + kk];
            fma4(acc[i], a, w0, w1, w2, w3);
        }
    }

    const float4 as4 = ((const float4*)a_src)[tc];
    const float4 ad4 = ((const float4*)a_dst)[tc];
    #pragma unroll
    for (int i = 0; i < 4; ++i) {
        int r = row0 + 4 * tr + i;
        if (r < N_NODES) {
            ((ushort4*)t2b)[r * 8 + tc] =
                make_ushort4(f2bf(acc[i].x), f2bf(acc[i].y),
                             f2bf(acc[i].z), f2bf(acc[i].w));
            float s = dot4(acc[i], as4);
            float d = dot4(acc[i], ad4);
            s += __shfl_xor(s, 1); s += __shfl_xor(s, 2); s += __shfl_xor(s, 4);
            d += __shfl_xor(d, 1); d += __shfl_xor(d, 2); d += __shfl_xor(d, 4);
            if (tc == 0) {
                al_src[r] = s;
                al_dst[r] = d;
            }
        }
    }
}

// ---------------- agg2: one wave per node, 4 edge slots x 16 lanes ----------------
__global__ __launch_bounds__(256) void k_agg2(
    const unsigned short* __restrict__ t2b, const float* __restrict__ al_src,
    const float* __restrict__ al_dst, const int* __restrict__ row_ptr,
    const int* __restrict__ csr_src, const float* __restrict__ b2,
    float* __restrict__ out)
{
    const int n = blockIdx.x * 4 + (threadIdx.x >> 6);
    const int l = threadIdx.x & 63;
    const int slot = l >> 4;
    const int f2   = l & 15;
    const unsigned int* t2u = (const unsigned int*)t2b;

    const float alD = al_dst[n];
    float denom = 0.f;
    float2 acc = make_float2(0.f, 0.f);
    if (slot == 0) {
        float w = __expf(leaky(al_src[n] + alD));
        float2 v = bf2f2(t2u[n * 16 + f2]);
        denom = w;
        acc = make_float2(w * v.x, w * v.y);
    }
    const int beg = row_ptr[n], end = row_ptr[n + 1];
    for (int j = beg + slot; j < end; j += 4) {
        int s = csr_src[j];
        float w = __expf(leaky(al_src[s] + alD));
        float2 v = bf2f2(t2u[s * 16 + f2]);
        denom += w;
        acc.x = fmaf(w, v.x, acc.x);
        acc.y = fmaf(w, v.y, acc.y);
    }
    acc.x += __shfl_xor(acc.x, 16); acc.y += __shfl_xor(acc.y, 16);
    denom += __shfl_xor(denom, 16);
    acc.x += __shfl_xor(acc.x, 32); acc.y += __shfl_xor(acc.y, 32);
    denom += __shfl_xor(denom, 32);

    const float2 bb = ((const float2*)b2)[f2];
    float ox = acc.x / denom + bb.x;
    float oy = acc.y / denom + bb.y;
    float m = fmaxf(ox, oy);
    for (int off = 8; off; off >>= 1) m = fmaxf(m, __shfl_xor(m, off));
    float ssum = __expf(ox - m) + __expf(oy - m);
    for (int off = 8; off; off >>= 1) ssum += __shfl_xor(ssum, off);
    float lg = __logf(ssum);
    if (l < 16)
        ((float2*)out)[n * 16 + f2] = make_float2(ox - m - lg, oy - m - lg);
}

extern "C" void kernel_launch(void* const* d_in, const int* in_sizes, int n_in,
                              void* d_out, int out_size, void* d_ws, size_t ws_size,
                              hipStream_t stream) {
    const float* x      = (const float*)d_in[0];
    const int*   src    = (const int*)d_in[1];
    const int*   dst    = (const int*)d_in[2];
    const float* W1     = (const float*)d_in[3];
    const float* a_src1 = (const float*)d_in[4];
    const float* a_dst1 = (const float*)d_in[5];
    const float* b1     = (const float*)d_in[6];
    const float* W2     = (const float*)d_in[7];
    const float* a_src2 = (const float*)d_in[8];
    const float* a_dst2 = (const float*)d_in[9];
    const float* b2     = (const float*)d_in[10];
    float* out = (float*)d_out;

    char* ws = (char*)d_ws;
    size_t off = 0;
    auto alloc = [&](size_t bytes) {
        void* p = ws + off;
        off += (bytes + 255) & ~(size_t)255;
        return p;
    };
    unsigned short* h1b = (unsigned short*)alloc((size_t)N_NODES * 128 * 2);
    float*          h2  = (float*)alloc((size_t)N_NODES * 128 * 4);
    unsigned short* t2b = (unsigned short*)alloc((size_t)N_NODES * 32 * 2);
    float* alS1    = (float*)alloc((size_t)N_NODES * 8 * 4);
    float* alD1    = (float*)alloc((size_t)N_NODES * 8 * 4);
    float* alS2    = (float*)alloc((size_t)N_NODES * 4);
    float* alD2    = (float*)alloc((size_t)N_NODES * 4);
    int*   rowp    = (int*)alloc((size_t)(N_NODES + 1) * 4);
    int*   csr     = (int*)alloc((size_t)N_EDGES * 4);
    unsigned int* binned = (unsigned int*)alloc((size_t)N_EDGES * 4);
    int*   hist_g  = (int*)alloc((size_t)NBKT * NBKT * 4);    // 65536
    int*   offs    = (int*)alloc((size_t)NBKT * NBKT * 4);
    int*   partial = (int*)alloc((size_t)64 * 4);
    (void)ws_size; (void)in_sizes; (void)n_in; (void)out_size;

    const int row_tiles = (N_NODES + 63) / 64;   // 782

    k_hist<<<NBKT, 256, 0, stream>>>(dst, hist_g);
    k_scanA<<<64, 1024, 0, stream>>>(hist_g, partial);
    k_scanB<<<64, 1024, 0, stream>>>(hist_g, partial, offs);
    k_binscatter<<<NBKT, 256, 0, stream>>>(src, dst, offs, binned);
    k_csr_fine<<<NBKT, 256, 0, stream>>>(binned, offs, rowp, csr);
    k_gemm1<<<row_tiles * 2, 256, 0, stream>>>(x, W1, a_src1, a_dst1, h1b, alS1, alD1);
    k_agg1<<<N_NODES / 4, 256, 0, stream>>>(h1b, alS1, alD1, rowp, csr, b1, h2);
    k_gemm2<<<row_tiles, 128, 0, stream>>>(h2, W2, a_src2, a_dst2, t2b, alS2, alD2);
    k_agg2<<<N_NODES / 4, 256, 0, stream>>>(t2b, alS2, alD2, rowp, csr, b2, out);
}